// Round 7
// baseline (1125.708 us; speedup 1.0000x reference)
//
#include <hip/hip_runtime.h>

#define NN 50000
#define NP 50048  // padded to multiple of 64
#define NE 800000
#define ET (NE + NN)
#define SCAN_B ((NN + 255) / 256)  // 196 blocks

typedef __attribute__((ext_vector_type(8))) short short8;
typedef __attribute__((ext_vector_type(4))) float f32x4;

static __device__ __forceinline__ float bf2f(unsigned short u) {
  union { unsigned int i; float f; } v; v.i = ((unsigned int)u) << 16; return v.f;
}
static __device__ __forceinline__ unsigned short f2bf(float f) {
  union { unsigned int i; float f; } v; v.f = f;
  unsigned int r = v.i + 0x7fffu + ((v.i >> 16) & 1u);
  return (unsigned short)(r >> 16);
}
static __device__ __forceinline__ float lrelu(float z) { return z > 0.f ? z : 0.2f * z; }

// W1[128][256] -> Wt_hi/Wt_lo[256][128] (transposed, split)
__global__ void k_conv_w(const float* __restrict__ W1, unsigned short* __restrict__ wh,
                         unsigned short* __restrict__ wl) {
  int i = blockIdx.x * 256 + threadIdx.x;
  if (i >= 32768) return;
  int k = i >> 8, n = i & 255;
  float v = W1[i];
  unsigned short hi = f2bf(v);
  wh[n * 128 + k] = hi;
  wl[n * 128 + k] = f2bf(v - bf2f(hi));
}

// ---------------- CSR build ----------------
__global__ void k_count(const int* __restrict__ ei, int* __restrict__ counts) {
  int e = blockIdx.x * blockDim.x + threadIdx.x;
  if (e >= ET) return;
  int dst = (e < NE) ? ei[NE + e] : (e - NE);
  atomicAdd(&counts[dst], 1);
}

__global__ __launch_bounds__(256) void k_scan_a(const int* __restrict__ counts,
                                                int* __restrict__ pre, int* __restrict__ bsum) {
  __shared__ int sa[256];
  __shared__ int sb[256];
  const int t = threadIdx.x;
  const int i = blockIdx.x * 256 + t;
  sa[t] = (i < NN) ? counts[i] : 0;
  __syncthreads();
  int* src = sa;
  int* dst = sb;
  for (int off = 1; off < 256; off <<= 1) {
    int v = src[t];
    if (t >= off) v += src[t - off];
    dst[t] = v;
    int* tmp = src; src = dst; dst = tmp;
    __syncthreads();
  }
  int excl = (t == 0) ? 0 : src[t - 1];
  if (i < NN) pre[i] = excl;
  if (t == 255) bsum[blockIdx.x] = src[255];
}

__global__ __launch_bounds__(256) void k_scan_b(int* __restrict__ bsum, int* __restrict__ row_ptr) {
  __shared__ int sa[256];
  __shared__ int sb[256];
  const int t = threadIdx.x;
  sa[t] = (t < SCAN_B) ? bsum[t] : 0;
  __syncthreads();
  int* src = sa;
  int* dst = sb;
  for (int off = 1; off < 256; off <<= 1) {
    int v = src[t];
    if (t >= off) v += src[t - off];
    dst[t] = v;
    int* tmp = src; src = dst; dst = tmp;
    __syncthreads();
  }
  int excl = (t == 0) ? 0 : src[t - 1];
  if (t < SCAN_B) bsum[t] = excl;
  if (t == 255) row_ptr[NN] = src[255];
}

__global__ __launch_bounds__(256) void k_scan_c(const int* __restrict__ pre,
                                                const int* __restrict__ bsum,
                                                int* __restrict__ row_ptr,
                                                int* __restrict__ cursor) {
  int i = blockIdx.x * 256 + threadIdx.x;
  if (i >= NN) return;
  int v = bsum[blockIdx.x] + pre[i];
  row_ptr[i] = v;
  cursor[i] = v;
}

__global__ void k_scatter(const int* __restrict__ ei, int* __restrict__ cursor,
                          int* __restrict__ ssrc) {
  int e = blockIdx.x * blockDim.x + threadIdx.x;
  if (e >= ET) return;
  int src = (e < NE) ? ei[e] : (e - NE);
  int dst = (e < NE) ? ei[NE + e] : (e - NE);
  int pos = atomicAdd(&cursor[dst], 1);
  ssrc[pos] = src;
}

// ---------------- Layer-1 GEMM via MFMA bf16x2 (3-pass split), fp32 A split in-kernel ----------------
__global__ __launch_bounds__(256) void k_gemm1(
    const float* __restrict__ x,
    const unsigned short* __restrict__ wh, const unsigned short* __restrict__ wl,
    const float* __restrict__ a1s, const float* __restrict__ a1d,
    unsigned short* __restrict__ h1, float* __restrict__ as1, float* __restrict__ ad1) {
  __shared__ unsigned short hst[64][264];
  const int tid = threadIdx.x;
  const int w = tid >> 6, lane = tid & 63;
  const int quad = lane >> 4, m16 = lane & 15;
  const int row0 = blockIdx.x * 64;
  const int koff = quad * 8;

  f32x4 acc[4][4];
  for (int mt = 0; mt < 4; ++mt)
    for (int nt = 0; nt < 4; ++nt) acc[mt][nt] = (f32x4){0.f, 0.f, 0.f, 0.f};

  for (int kt = 0; kt < 4; ++kt) {
    short8 ah[4], al[4], bh[4], bl[4];
    for (int mt = 0; mt < 4; ++mt) {
      int row = row0 + mt * 16 + m16;
      float vv[8];
      if (row < NN) {
        const float4* p = (const float4*)(x + (size_t)row * 128 + kt * 32 + koff);
        float4 f0 = p[0], f1 = p[1];
        vv[0] = f0.x; vv[1] = f0.y; vv[2] = f0.z; vv[3] = f0.w;
        vv[4] = f1.x; vv[5] = f1.y; vv[6] = f1.z; vv[7] = f1.w;
      } else {
        for (int j = 0; j < 8; ++j) vv[j] = 0.f;
      }
#pragma unroll
      for (int j = 0; j < 8; ++j) {
        unsigned short hi = f2bf(vv[j]);
        ah[mt][j] = (short)hi;
        al[mt][j] = (short)f2bf(vv[j] - bf2f(hi));
      }
    }
    for (int nt = 0; nt < 4; ++nt) {
      size_t rb = (size_t)(w * 64 + nt * 16 + m16) * 128 + kt * 32 + koff;
      bh[nt] = *(const short8*)(wh + rb);
      bl[nt] = *(const short8*)(wl + rb);
    }
    for (int mt = 0; mt < 4; ++mt)
      for (int nt = 0; nt < 4; ++nt) {
        acc[mt][nt] = __builtin_amdgcn_mfma_f32_16x16x32_bf16(ah[mt], bh[nt], acc[mt][nt], 0, 0, 0);
        acc[mt][nt] = __builtin_amdgcn_mfma_f32_16x16x32_bf16(ah[mt], bl[nt], acc[mt][nt], 0, 0, 0);
        acc[mt][nt] = __builtin_amdgcn_mfma_f32_16x16x32_bf16(al[mt], bh[nt], acc[mt][nt], 0, 0, 0);
      }
  }
  for (int mt = 0; mt < 4; ++mt)
    for (int nt = 0; nt < 4; ++nt) {
      int c = w * 64 + nt * 16 + m16;
      int rb = mt * 16 + quad * 4;
      for (int r = 0; r < 4; ++r) hst[rb + r][c] = f2bf(acc[mt][nt][r]);
    }
  __syncthreads();
  for (int p = 0; p < 8; ++p) {
    int idx = p * 256 + tid;
    int row = idx >> 5, u4 = idx & 31;
    int grow = row0 + row;
    if (grow < NN) {
      uint4 v = *(const uint4*)&hst[row][u4 * 8];
      *(uint4*)(h1 + (size_t)grow * 256 + u4 * 8) = v;
    }
  }
  for (int p = 0; p < 2; ++p) {
    int id = p * 256 + tid;
    int row = id >> 3, head = id & 7;
    int grow = row0 + row;
    if (grow < NN) {
      float sa = 0.f, sd = 0.f;
      for (int c = 0; c < 32; ++c) {
        float hv = bf2f(hst[row][head * 32 + c]);
        sa = fmaf(hv, a1s[head * 32 + c], sa);
        sd = fmaf(hv, a1d[head * 32 + c], sd);
      }
      as1[(size_t)grow * 8 + head] = sa;
      ad1[(size_t)grow * 8 + head] = sd;
    }
  }
}

// ---------------- Layer-1 aggregation (wave per dst), pipelined batches ----------------
__global__ __launch_bounds__(256) void k_agg1(
    const int* __restrict__ row_ptr, const int* __restrict__ ssrc,
    const unsigned short* __restrict__ h1, const float* __restrict__ as1,
    const float* __restrict__ ad1, const float* __restrict__ b1,
    const float* __restrict__ W2, const float* __restrict__ a2s,
    const float* __restrict__ a2d, float* __restrict__ t_out,
    float* __restrict__ s2_out, float* __restrict__ d2_out) {
  const int lane = threadIdx.x & 63;
  const int dst = (int)((blockIdx.x * blockDim.x + threadIdx.x) >> 6);
  if (dst >= NN) return;  // wave-uniform
  const int start = row_ptr[dst], end = row_ptr[dst + 1];
  const int hA = lane & 7;
  const int eoff = lane >> 3;
  const float ad_h = ad1[(size_t)dst * 8 + hA];
  // pass 1: softmax denominator (no max-shift: logits bounded, exp-safe)
  float s_loc = 0.f;
  for (int base = start; base < end; base += 8) {
    int e = base + eoff;
    if (e < end) {
      int src = ssrc[e];
      s_loc += __expf(lrelu(as1[(size_t)src * 8 + hA] + ad_h));
    }
  }
  s_loc += __shfl_xor(s_loc, 8);
  s_loc += __shfl_xor(s_loc, 16);
  s_loc += __shfl_xor(s_loc, 32);
  const float inv_s = 1.f / (s_loc + 1e-16f);
  // pass 2 (round-5 mapping, software-pipelined): lane owns (head hB, 4 ch at cB).
  // Hoist 8 shuffles, issue 8 independent loads, then FMA. Lanes past end: se=0,w=0.
  const int hB = lane >> 3;
  const int cB = (lane & 7) * 4;
  float acc0 = 0.f, acc1 = 0.f, acc2 = 0.f, acc3 = 0.f;
  for (int base = start; base < end; base += 8) {
    int e = base + eoff;
    int srcv = 0;
    float wv = 0.f;
    if (e < end) {
      srcv = ssrc[e];
      wv = __expf(lrelu(as1[(size_t)srcv * 8 + hA] + ad_h)) * inv_s;
    }
    int se[8];
    float w8[8];
#pragma unroll
    for (int stp = 0; stp < 8; ++stp) {
      se[stp] = __shfl(srcv, stp * 8);
      w8[stp] = __shfl(wv, stp * 8 + hB);
    }
    uint2 u[8];
#pragma unroll
    for (int stp = 0; stp < 8; ++stp)
      u[stp] = *(const uint2*)(h1 + (size_t)se[stp] * 256 + hB * 32 + cB);
#pragma unroll
    for (int stp = 0; stp < 8; ++stp) {
      float w = w8[stp];
      acc0 = fmaf(w, bf2f((unsigned short)(u[stp].x & 0xffffu)), acc0);
      acc1 = fmaf(w, bf2f((unsigned short)(u[stp].x >> 16)), acc1);
      acc2 = fmaf(w, bf2f((unsigned short)(u[stp].y & 0xffffu)), acc2);
      acc3 = fmaf(w, bf2f((unsigned short)(u[stp].y >> 16)), acc3);
    }
  }
  // fused epilogue: +b1, ELU, @W2 (256->2)
  const int col = hB * 32 + cB;
  float av[4] = {acc0, acc1, acc2, acc3};
  float tp0 = 0.f, tp1 = 0.f;
  for (int j = 0; j < 4; ++j) {
    float v = av[j] + b1[col + j];
    v = v > 0.f ? v : (__expf(v) - 1.f);  // ELU
    tp0 = fmaf(v, W2[(col + j) * 2 + 0], tp0);
    tp1 = fmaf(v, W2[(col + j) * 2 + 1], tp1);
  }
  for (int off = 32; off >= 1; off >>= 1) {
    tp0 += __shfl_xor(tp0, off);
    tp1 += __shfl_xor(tp1, off);
  }
  if (lane == 0) {
    t_out[(size_t)dst * 2 + 0] = tp0;
    t_out[(size_t)dst * 2 + 1] = tp1;
    s2_out[dst] = tp0 * a2s[0] + tp1 * a2s[1];
    d2_out[dst] = tp0 * a2d[0] + tp1 * a2d[1];
  }
}

// ---------------- Layer-2 aggregation (thread per dst) ----------------
__global__ void k_agg2(const int* __restrict__ row_ptr, const int* __restrict__ ssrc,
                       const float* __restrict__ t_in, const float* __restrict__ s2,
                       const float* __restrict__ d2, const float* __restrict__ b2,
                       float* __restrict__ out) {
  int n = blockIdx.x * blockDim.x + threadIdx.x;
  if (n >= NN) return;
  int st = row_ptr[n], en = row_ptr[n + 1];
  float dv = d2[n];
  float ssum = 0.f;
  for (int e = st; e < en; ++e) ssum += __expf(lrelu(s2[ssrc[e]] + dv));
  float inv = 1.f / (ssum + 1e-16f);
  float o0 = 0.f, o1 = 0.f;
  for (int e = st; e < en; ++e) {
    int s = ssrc[e];
    float w = __expf(lrelu(s2[s] + dv)) * inv;
    o0 = fmaf(w, t_in[(size_t)s * 2 + 0], o0);
    o1 = fmaf(w, t_in[(size_t)s * 2 + 1], o1);
  }
  out[(size_t)n * 2 + 0] = o0 + b2[0];
  out[(size_t)n * 2 + 1] = o1 + b2[1];
}

extern "C" void kernel_launch(void* const* d_in, const int* in_sizes, int n_in,
                              void* d_out, int out_size, void* d_ws, size_t ws_size,
                              hipStream_t stream) {
  const float* x = (const float*)d_in[0];
  const int* ei = (const int*)d_in[1];
  // d_in[2] = batch (unused)
  const float* W1 = (const float*)d_in[3];
  const float* a1s = (const float*)d_in[4];
  const float* a1d = (const float*)d_in[5];
  const float* b1 = (const float*)d_in[6];
  const float* W2 = (const float*)d_in[7];
  const float* a2s = (const float*)d_in[8];
  const float* a2d = (const float*)d_in[9];
  const float* b2 = (const float*)d_in[10];
  float* out = (float*)d_out;

  char* ws = (char*)d_ws;
  size_t off = 0;
  auto alloc = [&](size_t bytes) -> void* {
    void* p = ws + off;
    off += (bytes + 255) & ~(size_t)255;
    return p;
  };
  int* counts = (int*)alloc((size_t)NN * 4);
  int* row_ptr = (int*)alloc((size_t)(NN + 1) * 4);
  int* cursor = (int*)alloc((size_t)NN * 4);
  int* pre = (int*)alloc((size_t)NN * 4);
  int* bsum = (int*)alloc((size_t)SCAN_B * 4);
  int* ssrc = (int*)alloc((size_t)ET * 4);
  unsigned short* wh = (unsigned short*)alloc((size_t)32768 * 2);
  unsigned short* wl = (unsigned short*)alloc((size_t)32768 * 2);
  unsigned short* h1 = (unsigned short*)alloc((size_t)NN * 256 * 2);
  float* as1 = (float*)alloc((size_t)NN * 8 * 4);
  float* ad1 = (float*)alloc((size_t)NN * 8 * 4);
  float* t = (float*)alloc((size_t)NN * 2 * 4);
  float* s2 = (float*)alloc((size_t)NN * 4);
  float* d2v = (float*)alloc((size_t)NN * 4);
  (void)ws_size; (void)in_sizes; (void)n_in; (void)out_size;

  hipMemsetAsync(counts, 0, (size_t)NN * 4, stream);
  k_conv_w<<<128, 256, 0, stream>>>(W1, wh, wl);
  k_count<<<(ET + 255) / 256, 256, 0, stream>>>(ei, counts);
  k_scan_a<<<SCAN_B, 256, 0, stream>>>(counts, pre, bsum);
  k_scan_b<<<1, 256, 0, stream>>>(bsum, row_ptr);
  k_scan_c<<<SCAN_B, 256, 0, stream>>>(pre, bsum, row_ptr, cursor);
  k_scatter<<<(ET + 255) / 256, 256, 0, stream>>>(ei, cursor, ssrc);
  k_gemm1<<<NP / 64, 256, 0, stream>>>(x, wh, wl, a1s, a1d, h1, as1, ad1);
  k_agg1<<<(NN + 3) / 4, 256, 0, stream>>>(row_ptr, ssrc, h1, as1, ad1, b1, W2, a2s, a2d, t, s2, d2v);
  k_agg2<<<(NN + 255) / 256, 256, 0, stream>>>(row_ptr, ssrc, t, s2, d2v, b2, out);
}

// Round 8
// 339.644 us; speedup vs baseline: 3.3144x; 3.3144x over previous
//
#include <hip/hip_runtime.h>

#define NN 50000
#define NP 50048  // padded to multiple of 64
#define NE 800000
#define ET (NE + NN)
#define SCAN_B ((NN + 255) / 256)  // 196 blocks

typedef __attribute__((ext_vector_type(8))) short short8;
typedef __attribute__((ext_vector_type(4))) float f32x4;

static __device__ __forceinline__ float bf2f(unsigned short u) {
  union { unsigned int i; float f; } v; v.i = ((unsigned int)u) << 16; return v.f;
}
static __device__ __forceinline__ unsigned short f2bf(float f) {
  union { unsigned int i; float f; } v; v.f = f;
  unsigned int r = v.i + 0x7fffu + ((v.i >> 16) & 1u);
  return (unsigned short)(r >> 16);
}
static __device__ __forceinline__ float lrelu(float z) { return z > 0.f ? z : 0.2f * z; }

// ---------------- bf16x2 split conversions ----------------
__global__ void k_conv_x(const float* __restrict__ x, unsigned short* __restrict__ xh,
                         unsigned short* __restrict__ xl) {
  int i4 = blockIdx.x * 256 + threadIdx.x;  // handles 4 elements
  if (i4 >= NP * 32) return;
  int i = i4 * 4;
  int row = i >> 7;
  float4 v = (row < NN) ? *(const float4*)(x + i) : (float4){0.f, 0.f, 0.f, 0.f};
  float vv[4] = {v.x, v.y, v.z, v.w};
  ushort4 h, l;
  unsigned short* hp = (unsigned short*)&h;
  unsigned short* lp = (unsigned short*)&l;
#pragma unroll
  for (int j = 0; j < 4; ++j) {
    unsigned short hi = f2bf(vv[j]);
    hp[j] = hi;
    lp[j] = f2bf(vv[j] - bf2f(hi));
  }
  *(ushort4*)(xh + i) = h;
  *(ushort4*)(xl + i) = l;
}

// W1[128][256] -> Wt_hi/Wt_lo[256][128] (transposed, split)
__global__ void k_conv_w(const float* __restrict__ W1, unsigned short* __restrict__ wh,
                         unsigned short* __restrict__ wl) {
  int i = blockIdx.x * 256 + threadIdx.x;
  if (i >= 32768) return;
  int k = i >> 8, n = i & 255;
  float v = W1[i];
  unsigned short hi = f2bf(v);
  wh[n * 128 + k] = hi;
  wl[n * 128 + k] = f2bf(v - bf2f(hi));
}

// ---------------- CSR build ----------------
__global__ void k_count(const int* __restrict__ ei, int* __restrict__ counts) {
  int e = blockIdx.x * blockDim.x + threadIdx.x;
  if (e >= ET) return;
  int dst = (e < NE) ? ei[NE + e] : (e - NE);
  atomicAdd(&counts[dst], 1);
}

__global__ __launch_bounds__(256) void k_scan_a(const int* __restrict__ counts,
                                                int* __restrict__ pre, int* __restrict__ bsum) {
  __shared__ int sa[256];
  __shared__ int sb[256];
  const int t = threadIdx.x;
  const int i = blockIdx.x * 256 + t;
  sa[t] = (i < NN) ? counts[i] : 0;
  __syncthreads();
  int* src = sa;
  int* dst = sb;
  for (int off = 1; off < 256; off <<= 1) {
    int v = src[t];
    if (t >= off) v += src[t - off];
    dst[t] = v;
    int* tmp = src; src = dst; dst = tmp;
    __syncthreads();
  }
  int excl = (t == 0) ? 0 : src[t - 1];
  if (i < NN) pre[i] = excl;
  if (t == 255) bsum[blockIdx.x] = src[255];
}

__global__ __launch_bounds__(256) void k_scan_b(int* __restrict__ bsum, int* __restrict__ row_ptr) {
  __shared__ int sa[256];
  __shared__ int sb[256];
  const int t = threadIdx.x;
  sa[t] = (t < SCAN_B) ? bsum[t] : 0;
  __syncthreads();
  int* src = sa;
  int* dst = sb;
  for (int off = 1; off < 256; off <<= 1) {
    int v = src[t];
    if (t >= off) v += src[t - off];
    dst[t] = v;
    int* tmp = src; src = dst; dst = tmp;
    __syncthreads();
  }
  int excl = (t == 0) ? 0 : src[t - 1];
  if (t < SCAN_B) bsum[t] = excl;
  if (t == 255) row_ptr[NN] = src[255];
}

__global__ __launch_bounds__(256) void k_scan_c(const int* __restrict__ pre,
                                                const int* __restrict__ bsum,
                                                int* __restrict__ row_ptr,
                                                int* __restrict__ cursor) {
  int i = blockIdx.x * 256 + threadIdx.x;
  if (i >= NN) return;
  int v = bsum[blockIdx.x] + pre[i];
  row_ptr[i] = v;
  cursor[i] = v;
}

__global__ void k_scatter(const int* __restrict__ ei, int* __restrict__ cursor,
                          int* __restrict__ ssrc) {
  int e = blockIdx.x * blockDim.x + threadIdx.x;
  if (e >= ET) return;
  int src = (e < NE) ? ei[e] : (e - NE);
  int dst = (e < NE) ? ei[NE + e] : (e - NE);
  int pos = atomicAdd(&cursor[dst], 1);
  ssrc[pos] = src;
}

// ---------------- Layer-1 GEMM via MFMA bf16x2 (3-pass split) ----------------
// Round-5 verified-fast version: direct short8 fragment loads from pre-split xh/xl.
__global__ __launch_bounds__(256) void k_gemm1(
    const unsigned short* __restrict__ xh, const unsigned short* __restrict__ xl,
    const unsigned short* __restrict__ wh, const unsigned short* __restrict__ wl,
    const float* __restrict__ a1s, const float* __restrict__ a1d,
    unsigned short* __restrict__ h1, float* __restrict__ as1, float* __restrict__ ad1) {
  __shared__ unsigned short hst[64][264];
  const int tid = threadIdx.x;
  const int w = tid >> 6, lane = tid & 63;
  const int quad = lane >> 4, m16 = lane & 15;
  const int row0 = blockIdx.x * 64;
  const int koff = quad * 8;

  f32x4 acc[4][4];
  for (int mt = 0; mt < 4; ++mt)
    for (int nt = 0; nt < 4; ++nt) acc[mt][nt] = (f32x4){0.f, 0.f, 0.f, 0.f};

  for (int kt = 0; kt < 4; ++kt) {
    short8 ah[4], al[4], bh[4], bl[4];
    for (int mt = 0; mt < 4; ++mt) {
      size_t ra = (size_t)(row0 + mt * 16 + m16) * 128 + kt * 32 + koff;
      ah[mt] = *(const short8*)(xh + ra);
      al[mt] = *(const short8*)(xl + ra);
    }
    for (int nt = 0; nt < 4; ++nt) {
      size_t rb = (size_t)(w * 64 + nt * 16 + m16) * 128 + kt * 32 + koff;
      bh[nt] = *(const short8*)(wh + rb);
      bl[nt] = *(const short8*)(wl + rb);
    }
    for (int mt = 0; mt < 4; ++mt)
      for (int nt = 0; nt < 4; ++nt) {
        acc[mt][nt] = __builtin_amdgcn_mfma_f32_16x16x32_bf16(ah[mt], bh[nt], acc[mt][nt], 0, 0, 0);
        acc[mt][nt] = __builtin_amdgcn_mfma_f32_16x16x32_bf16(ah[mt], bl[nt], acc[mt][nt], 0, 0, 0);
        acc[mt][nt] = __builtin_amdgcn_mfma_f32_16x16x32_bf16(al[mt], bh[nt], acc[mt][nt], 0, 0, 0);
      }
  }
  for (int mt = 0; mt < 4; ++mt)
    for (int nt = 0; nt < 4; ++nt) {
      int c = w * 64 + nt * 16 + m16;
      int rb = mt * 16 + quad * 4;
      for (int r = 0; r < 4; ++r) hst[rb + r][c] = f2bf(acc[mt][nt][r]);
    }
  __syncthreads();
  for (int p = 0; p < 8; ++p) {
    int idx = p * 256 + tid;
    int row = idx >> 5, u4 = idx & 31;
    int grow = row0 + row;
    if (grow < NN) {
      uint4 v = *(const uint4*)&hst[row][u4 * 8];
      *(uint4*)(h1 + (size_t)grow * 256 + u4 * 8) = v;
    }
  }
  for (int p = 0; p < 2; ++p) {
    int id = p * 256 + tid;
    int row = id >> 3, head = id & 7;
    int grow = row0 + row;
    if (grow < NN) {
      float sa = 0.f, sd = 0.f;
      for (int c = 0; c < 32; ++c) {
        float hv = bf2f(hst[row][head * 32 + c]);
        sa = fmaf(hv, a1s[head * 32 + c], sa);
        sd = fmaf(hv, a1d[head * 32 + c], sd);
      }
      as1[(size_t)grow * 8 + head] = sa;
      ad1[(size_t)grow * 8 + head] = sd;
    }
  }
}

// ---------------- Layer-1 aggregation (wave per dst), pipelined batches ----------------
__global__ __launch_bounds__(256) void k_agg1(
    const int* __restrict__ row_ptr, const int* __restrict__ ssrc,
    const unsigned short* __restrict__ h1, const float* __restrict__ as1,
    const float* __restrict__ ad1, const float* __restrict__ b1,
    const float* __restrict__ W2, const float* __restrict__ a2s,
    const float* __restrict__ a2d, float* __restrict__ t_out,
    float* __restrict__ s2_out, float* __restrict__ d2_out) {
  const int lane = threadIdx.x & 63;
  const int dst = (int)((blockIdx.x * blockDim.x + threadIdx.x) >> 6);
  if (dst >= NN) return;  // wave-uniform
  const int start = row_ptr[dst], end = row_ptr[dst + 1];
  const int hA = lane & 7;
  const int eoff = lane >> 3;
  const float ad_h = ad1[(size_t)dst * 8 + hA];
  // pass 1: softmax denominator (no max-shift: logits bounded, exp-safe)
  float s_loc = 0.f;
  for (int base = start; base < end; base += 8) {
    int e = base + eoff;
    if (e < end) {
      int src = ssrc[e];
      s_loc += __expf(lrelu(as1[(size_t)src * 8 + hA] + ad_h));
    }
  }
  s_loc += __shfl_xor(s_loc, 8);
  s_loc += __shfl_xor(s_loc, 16);
  s_loc += __shfl_xor(s_loc, 32);
  const float inv_s = 1.f / (s_loc + 1e-16f);
  // pass 2: hoist 8 shuffles, issue 8 independent loads, then FMA.
  const int hB = lane >> 3;
  const int cB = (lane & 7) * 4;
  float acc0 = 0.f, acc1 = 0.f, acc2 = 0.f, acc3 = 0.f;
  for (int base = start; base < end; base += 8) {
    int e = base + eoff;
    int srcv = 0;
    float wv = 0.f;
    if (e < end) {
      srcv = ssrc[e];
      wv = __expf(lrelu(as1[(size_t)srcv * 8 + hA] + ad_h)) * inv_s;
    }
    int se[8];
    float w8[8];
#pragma unroll
    for (int stp = 0; stp < 8; ++stp) {
      se[stp] = __shfl(srcv, stp * 8);
      w8[stp] = __shfl(wv, stp * 8 + hB);
    }
    uint2 u[8];
#pragma unroll
    for (int stp = 0; stp < 8; ++stp)
      u[stp] = *(const uint2*)(h1 + (size_t)se[stp] * 256 + hB * 32 + cB);
#pragma unroll
    for (int stp = 0; stp < 8; ++stp) {
      float w = w8[stp];
      acc0 = fmaf(w, bf2f((unsigned short)(u[stp].x & 0xffffu)), acc0);
      acc1 = fmaf(w, bf2f((unsigned short)(u[stp].x >> 16)), acc1);
      acc2 = fmaf(w, bf2f((unsigned short)(u[stp].y & 0xffffu)), acc2);
      acc3 = fmaf(w, bf2f((unsigned short)(u[stp].y >> 16)), acc3);
    }
  }
  // fused epilogue: +b1, ELU, @W2 (256->2)
  const int col = hB * 32 + cB;
  float av[4] = {acc0, acc1, acc2, acc3};
  float tp0 = 0.f, tp1 = 0.f;
  for (int j = 0; j < 4; ++j) {
    float v = av[j] + b1[col + j];
    v = v > 0.f ? v : (__expf(v) - 1.f);  // ELU
    tp0 = fmaf(v, W2[(col + j) * 2 + 0], tp0);
    tp1 = fmaf(v, W2[(col + j) * 2 + 1], tp1);
  }
  for (int off = 32; off >= 1; off >>= 1) {
    tp0 += __shfl_xor(tp0, off);
    tp1 += __shfl_xor(tp1, off);
  }
  if (lane == 0) {
    t_out[(size_t)dst * 2 + 0] = tp0;
    t_out[(size_t)dst * 2 + 1] = tp1;
    s2_out[dst] = tp0 * a2s[0] + tp1 * a2s[1];
    d2_out[dst] = tp0 * a2d[0] + tp1 * a2d[1];
  }
}

// ---------------- Layer-2 aggregation (thread per dst) ----------------
__global__ void k_agg2(const int* __restrict__ row_ptr, const int* __restrict__ ssrc,
                       const float* __restrict__ t_in, const float* __restrict__ s2,
                       const float* __restrict__ d2, const float* __restrict__ b2,
                       float* __restrict__ out) {
  int n = blockIdx.x * blockDim.x + threadIdx.x;
  if (n >= NN) return;
  int st = row_ptr[n], en = row_ptr[n + 1];
  float dv = d2[n];
  float ssum = 0.f;
  for (int e = st; e < en; ++e) ssum += __expf(lrelu(s2[ssrc[e]] + dv));
  float inv = 1.f / (ssum + 1e-16f);
  float o0 = 0.f, o1 = 0.f;
  for (int e = st; e < en; ++e) {
    int s = ssrc[e];
    float w = __expf(lrelu(s2[s] + dv)) * inv;
    o0 = fmaf(w, t_in[(size_t)s * 2 + 0], o0);
    o1 = fmaf(w, t_in[(size_t)s * 2 + 1], o1);
  }
  out[(size_t)n * 2 + 0] = o0 + b2[0];
  out[(size_t)n * 2 + 1] = o1 + b2[1];
}

extern "C" void kernel_launch(void* const* d_in, const int* in_sizes, int n_in,
                              void* d_out, int out_size, void* d_ws, size_t ws_size,
                              hipStream_t stream) {
  const float* x = (const float*)d_in[0];
  const int* ei = (const int*)d_in[1];
  // d_in[2] = batch (unused)
  const float* W1 = (const float*)d_in[3];
  const float* a1s = (const float*)d_in[4];
  const float* a1d = (const float*)d_in[5];
  const float* b1 = (const float*)d_in[6];
  const float* W2 = (const float*)d_in[7];
  const float* a2s = (const float*)d_in[8];
  const float* a2d = (const float*)d_in[9];
  const float* b2 = (const float*)d_in[10];
  float* out = (float*)d_out;

  char* ws = (char*)d_ws;
  size_t off = 0;
  auto alloc = [&](size_t bytes) -> void* {
    void* p = ws + off;
    off += (bytes + 255) & ~(size_t)255;
    return p;
  };
  int* counts = (int*)alloc((size_t)NN * 4);
  int* row_ptr = (int*)alloc((size_t)(NN + 1) * 4);
  int* cursor = (int*)alloc((size_t)NN * 4);
  int* pre = (int*)alloc((size_t)NN * 4);
  int* bsum = (int*)alloc((size_t)SCAN_B * 4);
  int* ssrc = (int*)alloc((size_t)ET * 4);
  unsigned short* xh = (unsigned short*)alloc((size_t)NP * 128 * 2);
  unsigned short* xl = (unsigned short*)alloc((size_t)NP * 128 * 2);
  unsigned short* wh = (unsigned short*)alloc((size_t)32768 * 2);
  unsigned short* wl = (unsigned short*)alloc((size_t)32768 * 2);
  unsigned short* h1 = (unsigned short*)alloc((size_t)NN * 256 * 2);
  float* as1 = (float*)alloc((size_t)NN * 8 * 4);
  float* ad1 = (float*)alloc((size_t)NN * 8 * 4);
  float* t = (float*)alloc((size_t)NN * 2 * 4);
  float* s2 = (float*)alloc((size_t)NN * 4);
  float* d2v = (float*)alloc((size_t)NN * 4);
  (void)ws_size; (void)in_sizes; (void)n_in; (void)out_size;

  hipMemsetAsync(counts, 0, (size_t)NN * 4, stream);
  k_conv_x<<<(NP * 32 + 255) / 256, 256, 0, stream>>>(x, xh, xl);
  k_conv_w<<<128, 256, 0, stream>>>(W1, wh, wl);
  k_count<<<(ET + 255) / 256, 256, 0, stream>>>(ei, counts);
  k_scan_a<<<SCAN_B, 256, 0, stream>>>(counts, pre, bsum);
  k_scan_b<<<1, 256, 0, stream>>>(bsum, row_ptr);
  k_scan_c<<<SCAN_B, 256, 0, stream>>>(pre, bsum, row_ptr, cursor);
  k_scatter<<<(ET + 255) / 256, 256, 0, stream>>>(ei, cursor, ssrc);
  k_gemm1<<<NP / 64, 256, 0, stream>>>(xh, xl, wh, wl, a1s, a1d, h1, as1, ad1);
  k_agg1<<<(NN + 3) / 4, 256, 0, stream>>>(row_ptr, ssrc, h1, as1, ad1, b1, W2, a2s, a2d, t, s2, d2v);
  k_agg2<<<(NN + 255) / 256, 256, 0, stream>>>(row_ptr, ssrc, t, s2, d2v, b2, out);
}

// Round 9
// 321.050 us; speedup vs baseline: 3.5063x; 1.0579x over previous
//
#include <hip/hip_runtime.h>

#define NN 50000
#define NP 50048  // padded to multiple of 64
#define NE 800000
#define ET (NE + NN)
#define SCAN_B ((NN + 255) / 256)  // 196 blocks

typedef __attribute__((ext_vector_type(8))) short short8;
typedef __attribute__((ext_vector_type(4))) float f32x4;

static __device__ __forceinline__ float bf2f(unsigned short u) {
  union { unsigned int i; float f; } v; v.i = ((unsigned int)u) << 16; return v.f;
}
static __device__ __forceinline__ unsigned short f2bf(float f) {
  union { unsigned int i; float f; } v; v.f = f;
  unsigned int r = v.i + 0x7fffu + ((v.i >> 16) & 1u);
  return (unsigned short)(r >> 16);
}
static __device__ __forceinline__ float lrelu(float z) { return z > 0.f ? z : 0.2f * z; }

// ---------------- bf16x2 split conversions ----------------
__global__ void k_conv_x(const float* __restrict__ x, unsigned short* __restrict__ xh,
                         unsigned short* __restrict__ xl) {
  int i4 = blockIdx.x * 256 + threadIdx.x;  // handles 4 elements
  if (i4 >= NP * 32) return;
  int i = i4 * 4;
  int row = i >> 7;
  float4 v = (row < NN) ? *(const float4*)(x + i) : (float4){0.f, 0.f, 0.f, 0.f};
  float vv[4] = {v.x, v.y, v.z, v.w};
  ushort4 h, l;
  unsigned short* hp = (unsigned short*)&h;
  unsigned short* lp = (unsigned short*)&l;
#pragma unroll
  for (int j = 0; j < 4; ++j) {
    unsigned short hi = f2bf(vv[j]);
    hp[j] = hi;
    lp[j] = f2bf(vv[j] - bf2f(hi));
  }
  *(ushort4*)(xh + i) = h;
  *(ushort4*)(xl + i) = l;
}

// W1[128][256] -> Wt_hi/Wt_lo[256][128] (transposed, split)
__global__ void k_conv_w(const float* __restrict__ W1, unsigned short* __restrict__ wh,
                         unsigned short* __restrict__ wl) {
  int i = blockIdx.x * 256 + threadIdx.x;
  if (i >= 32768) return;
  int k = i >> 8, n = i & 255;
  float v = W1[i];
  unsigned short hi = f2bf(v);
  wh[n * 128 + k] = hi;
  wl[n * 128 + k] = f2bf(v - bf2f(hi));
}

// ---------------- CSR build ----------------
__global__ void k_count(const int* __restrict__ ei, int* __restrict__ counts) {
  int e = blockIdx.x * blockDim.x + threadIdx.x;
  if (e >= ET) return;
  int dst = (e < NE) ? ei[NE + e] : (e - NE);
  atomicAdd(&counts[dst], 1);
}

__global__ __launch_bounds__(256) void k_scan_a(const int* __restrict__ counts,
                                                int* __restrict__ pre, int* __restrict__ bsum) {
  __shared__ int sa[256];
  __shared__ int sb[256];
  const int t = threadIdx.x;
  const int i = blockIdx.x * 256 + t;
  sa[t] = (i < NN) ? counts[i] : 0;
  __syncthreads();
  int* src = sa;
  int* dst = sb;
  for (int off = 1; off < 256; off <<= 1) {
    int v = src[t];
    if (t >= off) v += src[t - off];
    dst[t] = v;
    int* tmp = src; src = dst; dst = tmp;
    __syncthreads();
  }
  int excl = (t == 0) ? 0 : src[t - 1];
  if (i < NN) pre[i] = excl;
  if (t == 255) bsum[blockIdx.x] = src[255];
}

__global__ __launch_bounds__(256) void k_scan_b(int* __restrict__ bsum, int* __restrict__ row_ptr) {
  __shared__ int sa[256];
  __shared__ int sb[256];
  const int t = threadIdx.x;
  sa[t] = (t < SCAN_B) ? bsum[t] : 0;
  __syncthreads();
  int* src = sa;
  int* dst = sb;
  for (int off = 1; off < 256; off <<= 1) {
    int v = src[t];
    if (t >= off) v += src[t - off];
    dst[t] = v;
    int* tmp = src; src = dst; dst = tmp;
    __syncthreads();
  }
  int excl = (t == 0) ? 0 : src[t - 1];
  if (t < SCAN_B) bsum[t] = excl;
  if (t == 255) row_ptr[NN] = src[255];
}

__global__ __launch_bounds__(256) void k_scan_c(const int* __restrict__ pre,
                                                const int* __restrict__ bsum,
                                                int* __restrict__ row_ptr,
                                                int* __restrict__ cursor) {
  int i = blockIdx.x * 256 + threadIdx.x;
  if (i >= NN) return;
  int v = bsum[blockIdx.x] + pre[i];
  row_ptr[i] = v;
  cursor[i] = v;
}

__global__ void k_scatter(const int* __restrict__ ei, int* __restrict__ cursor,
                          int* __restrict__ ssrc) {
  int e = blockIdx.x * blockDim.x + threadIdx.x;
  if (e >= ET) return;
  int src = (e < NE) ? ei[e] : (e - NE);
  int dst = (e < NE) ? ei[NE + e] : (e - NE);
  int pos = atomicAdd(&cursor[dst], 1);
  ssrc[pos] = src;
}

// ---------------- Layer-1 GEMM via MFMA bf16x2 (3-pass split) ----------------
__global__ __launch_bounds__(256) void k_gemm1(
    const unsigned short* __restrict__ xh, const unsigned short* __restrict__ xl,
    const unsigned short* __restrict__ wh, const unsigned short* __restrict__ wl,
    const float* __restrict__ a1s, const float* __restrict__ a1d,
    unsigned short* __restrict__ h1, float* __restrict__ as1, float* __restrict__ ad1) {
  __shared__ unsigned short hst[64][264];
  const int tid = threadIdx.x;
  const int w = tid >> 6, lane = tid & 63;
  const int quad = lane >> 4, m16 = lane & 15;
  const int row0 = blockIdx.x * 64;
  const int koff = quad * 8;

  f32x4 acc[4][4];
  for (int mt = 0; mt < 4; ++mt)
    for (int nt = 0; nt < 4; ++nt) acc[mt][nt] = (f32x4){0.f, 0.f, 0.f, 0.f};

  for (int kt = 0; kt < 4; ++kt) {
    short8 ah[4], al[4], bh[4], bl[4];
    for (int mt = 0; mt < 4; ++mt) {
      size_t ra = (size_t)(row0 + mt * 16 + m16) * 128 + kt * 32 + koff;
      ah[mt] = *(const short8*)(xh + ra);
      al[mt] = *(const short8*)(xl + ra);
    }
    for (int nt = 0; nt < 4; ++nt) {
      size_t rb = (size_t)(w * 64 + nt * 16 + m16) * 128 + kt * 32 + koff;
      bh[nt] = *(const short8*)(wh + rb);
      bl[nt] = *(const short8*)(wl + rb);
    }
    for (int mt = 0; mt < 4; ++mt)
      for (int nt = 0; nt < 4; ++nt) {
        acc[mt][nt] = __builtin_amdgcn_mfma_f32_16x16x32_bf16(ah[mt], bh[nt], acc[mt][nt], 0, 0, 0);
        acc[mt][nt] = __builtin_amdgcn_mfma_f32_16x16x32_bf16(ah[mt], bl[nt], acc[mt][nt], 0, 0, 0);
        acc[mt][nt] = __builtin_amdgcn_mfma_f32_16x16x32_bf16(al[mt], bh[nt], acc[mt][nt], 0, 0, 0);
      }
  }
  for (int mt = 0; mt < 4; ++mt)
    for (int nt = 0; nt < 4; ++nt) {
      int c = w * 64 + nt * 16 + m16;
      int rb = mt * 16 + quad * 4;
      for (int r = 0; r < 4; ++r) hst[rb + r][c] = f2bf(acc[mt][nt][r]);
    }
  __syncthreads();
  for (int p = 0; p < 8; ++p) {
    int idx = p * 256 + tid;
    int row = idx >> 5, u4 = idx & 31;
    int grow = row0 + row;
    if (grow < NN) {
      uint4 v = *(const uint4*)&hst[row][u4 * 8];
      *(uint4*)(h1 + (size_t)grow * 256 + u4 * 8) = v;
    }
  }
  for (int p = 0; p < 2; ++p) {
    int id = p * 256 + tid;
    int row = id >> 3, head = id & 7;
    int grow = row0 + row;
    if (grow < NN) {
      float sa = 0.f, sd = 0.f;
      for (int c = 0; c < 32; ++c) {
        float hv = bf2f(hst[row][head * 32 + c]);
        sa = fmaf(hv, a1s[head * 32 + c], sa);
        sd = fmaf(hv, a1d[head * 32 + c], sd);
      }
      as1[(size_t)grow * 8 + head] = sa;
      ad1[(size_t)grow * 8 + head] = sd;
    }
  }
}

// ---------------- Layer-1 aggregation: single fused pass, 16-edge batches ----------------
// Unnormalized accumulation (acc = Σ exp_e·h, s = Σ exp_e), scale by 1/s at end.
__global__ __launch_bounds__(256) void k_agg1(
    const int* __restrict__ row_ptr, const int* __restrict__ ssrc,
    const unsigned short* __restrict__ h1, const float* __restrict__ as1,
    const float* __restrict__ ad1, const float* __restrict__ b1,
    const float* __restrict__ W2, const float* __restrict__ a2s,
    const float* __restrict__ a2d, float* __restrict__ t_out,
    float* __restrict__ s2_out, float* __restrict__ d2_out) {
  const int lane = threadIdx.x & 63;
  const int dst = (int)((blockIdx.x * blockDim.x + threadIdx.x) >> 6);
  if (dst >= NN) return;  // wave-uniform
  const int start = row_ptr[dst], end = row_ptr[dst + 1];
  const int hA = lane & 7;
  const int eoff = lane >> 3;
  const int hB = lane >> 3;
  const int cB = (lane & 7) * 4;
  const float ad_h = ad1[(size_t)dst * 8 + hA];
  float s_loc = 0.f;
  float acc0 = 0.f, acc1 = 0.f, acc2 = 0.f, acc3 = 0.f;
  for (int base = start; base < end; base += 16) {
    int ea = base + eoff, eb = base + 8 + eoff;
    int sa_ = 0, sb_ = 0;
    float wa = 0.f, wb = 0.f;
    if (ea < end) {
      sa_ = ssrc[ea];
      wa = __expf(lrelu(as1[(size_t)sa_ * 8 + hA] + ad_h));
    }
    if (eb < end) {
      sb_ = ssrc[eb];
      wb = __expf(lrelu(as1[(size_t)sb_ * 8 + hA] + ad_h));
    }
    s_loc += wa + wb;
    uint2 u[16];
    float w16[16];
#pragma unroll
    for (int j = 0; j < 8; ++j) {
      int se = __shfl(sa_, j * 8);
      w16[j] = __shfl(wa, j * 8 + hB);
      u[j] = *(const uint2*)(h1 + (size_t)se * 256 + hB * 32 + cB);
    }
#pragma unroll
    for (int j = 0; j < 8; ++j) {
      int se = __shfl(sb_, j * 8);
      w16[8 + j] = __shfl(wb, j * 8 + hB);
      u[8 + j] = *(const uint2*)(h1 + (size_t)se * 256 + hB * 32 + cB);
    }
#pragma unroll
    for (int j = 0; j < 16; ++j) {
      float w = w16[j];
      acc0 = fmaf(w, bf2f((unsigned short)(u[j].x & 0xffffu)), acc0);
      acc1 = fmaf(w, bf2f((unsigned short)(u[j].x >> 16)), acc1);
      acc2 = fmaf(w, bf2f((unsigned short)(u[j].y & 0xffffu)), acc2);
      acc3 = fmaf(w, bf2f((unsigned short)(u[j].y >> 16)), acc3);
    }
  }
  // softmax denominator: reduce exp-sums over edge-groups; all lanes get s for their hA
  s_loc += __shfl_xor(s_loc, 8);
  s_loc += __shfl_xor(s_loc, 16);
  s_loc += __shfl_xor(s_loc, 32);
  const float inv_s = 1.f / (s_loc + 1e-16f);
  const float inv_sB = __shfl(inv_s, hB);  // lane hB holds s for head hB (its hA == hB)
  acc0 *= inv_sB; acc1 *= inv_sB; acc2 *= inv_sB; acc3 *= inv_sB;
  // fused epilogue: +b1, ELU, @W2 (256->2)
  const int col = hB * 32 + cB;
  float av[4] = {acc0, acc1, acc2, acc3};
  float tp0 = 0.f, tp1 = 0.f;
  for (int j = 0; j < 4; ++j) {
    float v = av[j] + b1[col + j];
    v = v > 0.f ? v : (__expf(v) - 1.f);  // ELU
    tp0 = fmaf(v, W2[(col + j) * 2 + 0], tp0);
    tp1 = fmaf(v, W2[(col + j) * 2 + 1], tp1);
  }
  for (int off = 32; off >= 1; off >>= 1) {
    tp0 += __shfl_xor(tp0, off);
    tp1 += __shfl_xor(tp1, off);
  }
  if (lane == 0) {
    t_out[(size_t)dst * 2 + 0] = tp0;
    t_out[(size_t)dst * 2 + 1] = tp1;
    s2_out[dst] = tp0 * a2s[0] + tp1 * a2s[1];
    d2_out[dst] = tp0 * a2d[0] + tp1 * a2d[1];
  }
}

// ---------------- Layer-2 aggregation: single fused pass (thread per dst) ----------------
__global__ void k_agg2(const int* __restrict__ row_ptr, const int* __restrict__ ssrc,
                       const float* __restrict__ t_in, const float* __restrict__ s2,
                       const float* __restrict__ d2, const float* __restrict__ b2,
                       float* __restrict__ out) {
  int n = blockIdx.x * blockDim.x + threadIdx.x;
  if (n >= NN) return;
  int st = row_ptr[n], en = row_ptr[n + 1];
  float dv = d2[n];
  float ssum = 0.f, o0 = 0.f, o1 = 0.f;
#pragma unroll 4
  for (int e = st; e < en; ++e) {
    int s = ssrc[e];
    float w = __expf(lrelu(s2[s] + dv));
    float2 tv = *(const float2*)(t_in + (size_t)s * 2);
    ssum += w;
    o0 = fmaf(w, tv.x, o0);
    o1 = fmaf(w, tv.y, o1);
  }
  float inv = 1.f / (ssum + 1e-16f);
  out[(size_t)n * 2 + 0] = o0 * inv + b2[0];
  out[(size_t)n * 2 + 1] = o1 * inv + b2[1];
}

extern "C" void kernel_launch(void* const* d_in, const int* in_sizes, int n_in,
                              void* d_out, int out_size, void* d_ws, size_t ws_size,
                              hipStream_t stream) {
  const float* x = (const float*)d_in[0];
  const int* ei = (const int*)d_in[1];
  // d_in[2] = batch (unused)
  const float* W1 = (const float*)d_in[3];
  const float* a1s = (const float*)d_in[4];
  const float* a1d = (const float*)d_in[5];
  const float* b1 = (const float*)d_in[6];
  const float* W2 = (const float*)d_in[7];
  const float* a2s = (const float*)d_in[8];
  const float* a2d = (const float*)d_in[9];
  const float* b2 = (const float*)d_in[10];
  float* out = (float*)d_out;

  char* ws = (char*)d_ws;
  size_t off = 0;
  auto alloc = [&](size_t bytes) -> void* {
    void* p = ws + off;
    off += (bytes + 255) & ~(size_t)255;
    return p;
  };
  int* counts = (int*)alloc((size_t)NN * 4);
  int* row_ptr = (int*)alloc((size_t)(NN + 1) * 4);
  int* cursor = (int*)alloc((size_t)NN * 4);
  int* pre = (int*)alloc((size_t)NN * 4);
  int* bsum = (int*)alloc((size_t)SCAN_B * 4);
  int* ssrc = (int*)alloc((size_t)ET * 4);
  unsigned short* xh = (unsigned short*)alloc((size_t)NP * 128 * 2);
  unsigned short* xl = (unsigned short*)alloc((size_t)NP * 128 * 2);
  unsigned short* wh = (unsigned short*)alloc((size_t)32768 * 2);
  unsigned short* wl = (unsigned short*)alloc((size_t)32768 * 2);
  unsigned short* h1 = (unsigned short*)alloc((size_t)NN * 256 * 2);
  float* as1 = (float*)alloc((size_t)NN * 8 * 4);
  float* ad1 = (float*)alloc((size_t)NN * 8 * 4);
  float* t = (float*)alloc((size_t)NN * 2 * 4);
  float* s2 = (float*)alloc((size_t)NN * 4);
  float* d2v = (float*)alloc((size_t)NN * 4);
  (void)ws_size; (void)in_sizes; (void)n_in; (void)out_size;

  hipMemsetAsync(counts, 0, (size_t)NN * 4, stream);
  k_conv_x<<<(NP * 32 + 255) / 256, 256, 0, stream>>>(x, xh, xl);
  k_conv_w<<<128, 256, 0, stream>>>(W1, wh, wl);
  k_count<<<(ET + 255) / 256, 256, 0, stream>>>(ei, counts);
  k_scan_a<<<SCAN_B, 256, 0, stream>>>(counts, pre, bsum);
  k_scan_b<<<1, 256, 0, stream>>>(bsum, row_ptr);
  k_scan_c<<<SCAN_B, 256, 0, stream>>>(pre, bsum, row_ptr, cursor);
  k_scatter<<<(ET + 255) / 256, 256, 0, stream>>>(ei, cursor, ssrc);
  k_gemm1<<<NP / 64, 256, 0, stream>>>(xh, xl, wh, wl, a1s, a1d, h1, as1, ad1);
  k_agg1<<<(NN + 3) / 4, 256, 0, stream>>>(row_ptr, ssrc, h1, as1, ad1, b1, W2, a2s, a2d, t, s2, d2v);
  k_agg2<<<(NN + 255) / 256, 256, 0, stream>>>(row_ptr, ssrc, t, s2, d2v, b2, out);
}

// Round 10
// 281.313 us; speedup vs baseline: 4.0016x; 1.1413x over previous
//
#include <hip/hip_runtime.h>

#define NN 50000
#define NP 50048  // padded to multiple of 64
#define NE 800000
#define ET (NE + NN)
#define SCAN_B ((NN + 255) / 256)  // 196 blocks

typedef __attribute__((ext_vector_type(8))) short short8;
typedef __attribute__((ext_vector_type(4))) float f32x4;

static __device__ __forceinline__ float bf2f(unsigned short u) {
  union { unsigned int i; float f; } v; v.i = ((unsigned int)u) << 16; return v.f;
}
static __device__ __forceinline__ unsigned short f2bf(float f) {
  union { unsigned int i; float f; } v; v.f = f;
  unsigned int r = v.i + 0x7fffu + ((v.i >> 16) & 1u);
  return (unsigned short)(r >> 16);
}
static __device__ __forceinline__ float lrelu(float z) { return z > 0.f ? z : 0.2f * z; }

// ---------------- bf16x2 split conversions ----------------
__global__ void k_conv_x(const float* __restrict__ x, unsigned short* __restrict__ xh,
                         unsigned short* __restrict__ xl) {
  int i4 = blockIdx.x * 256 + threadIdx.x;  // handles 4 elements
  if (i4 >= NP * 32) return;
  int i = i4 * 4;
  int row = i >> 7;
  float4 v = (row < NN) ? *(const float4*)(x + i) : (float4){0.f, 0.f, 0.f, 0.f};
  float vv[4] = {v.x, v.y, v.z, v.w};
  ushort4 h, l;
  unsigned short* hp = (unsigned short*)&h;
  unsigned short* lp = (unsigned short*)&l;
#pragma unroll
  for (int j = 0; j < 4; ++j) {
    unsigned short hi = f2bf(vv[j]);
    hp[j] = hi;
    lp[j] = f2bf(vv[j] - bf2f(hi));
  }
  *(ushort4*)(xh + i) = h;
  *(ushort4*)(xl + i) = l;
}

// W1[128][256] -> Wt_hi/Wt_lo[256][128] (transposed, split)
__global__ void k_conv_w(const float* __restrict__ W1, unsigned short* __restrict__ wh,
                         unsigned short* __restrict__ wl) {
  int i = blockIdx.x * 256 + threadIdx.x;
  if (i >= 32768) return;
  int k = i >> 8, n = i & 255;
  float v = W1[i];
  unsigned short hi = f2bf(v);
  wh[n * 128 + k] = hi;
  wl[n * 128 + k] = f2bf(v - bf2f(hi));
}

// ---------------- CSR build: single atomic pass (rank) + scan + non-atomic place ----------------
__global__ void k_rank(const int* __restrict__ ei, int* __restrict__ counts,
                       int* __restrict__ rank) {
  int e = blockIdx.x * blockDim.x + threadIdx.x;
  if (e >= ET) return;
  int dst = (e < NE) ? ei[NE + e] : (e - NE);
  rank[e] = atomicAdd(&counts[dst], 1);
}

__global__ __launch_bounds__(256) void k_scan_a(const int* __restrict__ counts,
                                                int* __restrict__ pre, int* __restrict__ bsum) {
  __shared__ int sa[256];
  __shared__ int sb[256];
  const int t = threadIdx.x;
  const int i = blockIdx.x * 256 + t;
  sa[t] = (i < NN) ? counts[i] : 0;
  __syncthreads();
  int* src = sa;
  int* dst = sb;
  for (int off = 1; off < 256; off <<= 1) {
    int v = src[t];
    if (t >= off) v += src[t - off];
    dst[t] = v;
    int* tmp = src; src = dst; dst = tmp;
    __syncthreads();
  }
  int excl = (t == 0) ? 0 : src[t - 1];
  if (i < NN) pre[i] = excl;
  if (t == 255) bsum[blockIdx.x] = src[255];
}

__global__ __launch_bounds__(256) void k_scan_b(int* __restrict__ bsum, int* __restrict__ row_ptr) {
  __shared__ int sa[256];
  __shared__ int sb[256];
  const int t = threadIdx.x;
  sa[t] = (t < SCAN_B) ? bsum[t] : 0;
  __syncthreads();
  int* src = sa;
  int* dst = sb;
  for (int off = 1; off < 256; off <<= 1) {
    int v = src[t];
    if (t >= off) v += src[t - off];
    dst[t] = v;
    int* tmp = src; src = dst; dst = tmp;
    __syncthreads();
  }
  int excl = (t == 0) ? 0 : src[t - 1];
  if (t < SCAN_B) bsum[t] = excl;
  if (t == 255) row_ptr[NN] = src[255];
}

__global__ __launch_bounds__(256) void k_scan_c(const int* __restrict__ pre,
                                                const int* __restrict__ bsum,
                                                int* __restrict__ row_ptr) {
  int i = blockIdx.x * 256 + threadIdx.x;
  if (i >= NN) return;
  row_ptr[i] = bsum[blockIdx.x] + pre[i];
}

__global__ void k_place(const int* __restrict__ ei, const int* __restrict__ row_ptr,
                        const int* __restrict__ rank, int* __restrict__ ssrc) {
  int e = blockIdx.x * blockDim.x + threadIdx.x;
  if (e >= ET) return;
  int src = (e < NE) ? ei[e] : (e - NE);
  int dst = (e < NE) ? ei[NE + e] : (e - NE);
  ssrc[row_ptr[dst] + rank[e]] = src;
}

// ---------------- Layer-1 GEMM via MFMA bf16x2 (3-pass split) ----------------
__global__ __launch_bounds__(256) void k_gemm1(
    const unsigned short* __restrict__ xh, const unsigned short* __restrict__ xl,
    const unsigned short* __restrict__ wh, const unsigned short* __restrict__ wl,
    const float* __restrict__ a1s, const float* __restrict__ a1d,
    unsigned short* __restrict__ h1, float* __restrict__ as1, float* __restrict__ ad1) {
  __shared__ unsigned short hst[64][264];
  const int tid = threadIdx.x;
  const int w = tid >> 6, lane = tid & 63;
  const int quad = lane >> 4, m16 = lane & 15;
  const int row0 = blockIdx.x * 64;
  const int koff = quad * 8;

  f32x4 acc[4][4];
  for (int mt = 0; mt < 4; ++mt)
    for (int nt = 0; nt < 4; ++nt) acc[mt][nt] = (f32x4){0.f, 0.f, 0.f, 0.f};

  for (int kt = 0; kt < 4; ++kt) {
    short8 ah[4], al[4], bh[4], bl[4];
    for (int mt = 0; mt < 4; ++mt) {
      size_t ra = (size_t)(row0 + mt * 16 + m16) * 128 + kt * 32 + koff;
      ah[mt] = *(const short8*)(xh + ra);
      al[mt] = *(const short8*)(xl + ra);
    }
    for (int nt = 0; nt < 4; ++nt) {
      size_t rb = (size_t)(w * 64 + nt * 16 + m16) * 128 + kt * 32 + koff;
      bh[nt] = *(const short8*)(wh + rb);
      bl[nt] = *(const short8*)(wl + rb);
    }
    for (int mt = 0; mt < 4; ++mt)
      for (int nt = 0; nt < 4; ++nt) {
        acc[mt][nt] = __builtin_amdgcn_mfma_f32_16x16x32_bf16(ah[mt], bh[nt], acc[mt][nt], 0, 0, 0);
        acc[mt][nt] = __builtin_amdgcn_mfma_f32_16x16x32_bf16(ah[mt], bl[nt], acc[mt][nt], 0, 0, 0);
        acc[mt][nt] = __builtin_amdgcn_mfma_f32_16x16x32_bf16(al[mt], bh[nt], acc[mt][nt], 0, 0, 0);
      }
  }
  for (int mt = 0; mt < 4; ++mt)
    for (int nt = 0; nt < 4; ++nt) {
      int c = w * 64 + nt * 16 + m16;
      int rb = mt * 16 + quad * 4;
      for (int r = 0; r < 4; ++r) hst[rb + r][c] = f2bf(acc[mt][nt][r]);
    }
  __syncthreads();
  for (int p = 0; p < 8; ++p) {
    int idx = p * 256 + tid;
    int row = idx >> 5, u4 = idx & 31;
    int grow = row0 + row;
    if (grow < NN) {
      uint4 v = *(const uint4*)&hst[row][u4 * 8];
      *(uint4*)(h1 + (size_t)grow * 256 + u4 * 8) = v;
    }
  }
  for (int p = 0; p < 2; ++p) {
    int id = p * 256 + tid;
    int row = id >> 3, head = id & 7;
    int grow = row0 + row;
    if (grow < NN) {
      float sa = 0.f, sd = 0.f;
      for (int c = 0; c < 32; ++c) {
        float hv = bf2f(hst[row][head * 32 + c]);
        sa = fmaf(hv, a1s[head * 32 + c], sa);
        sd = fmaf(hv, a1d[head * 32 + c], sd);
      }
      as1[(size_t)grow * 8 + head] = sa;
      ad1[(size_t)grow * 8 + head] = sd;
    }
  }
}

// ---------------- Layer-1 aggregation: single fused pass, 16-edge batches ----------------
__global__ __launch_bounds__(256) void k_agg1(
    const int* __restrict__ row_ptr, const int* __restrict__ ssrc,
    const unsigned short* __restrict__ h1, const float* __restrict__ as1,
    const float* __restrict__ ad1, const float* __restrict__ b1,
    const float* __restrict__ W2, const float* __restrict__ a2s,
    const float* __restrict__ a2d, float* __restrict__ t_out,
    float* __restrict__ s2_out, float* __restrict__ d2_out) {
  const int lane = threadIdx.x & 63;
  const int dst = (int)((blockIdx.x * blockDim.x + threadIdx.x) >> 6);
  if (dst >= NN) return;  // wave-uniform
  const int start = row_ptr[dst], end = row_ptr[dst + 1];
  const int hA = lane & 7;
  const int eoff = lane >> 3;
  const int hB = lane >> 3;
  const int cB = (lane & 7) * 4;
  const float ad_h = ad1[(size_t)dst * 8 + hA];
  float s_loc = 0.f;
  float acc0 = 0.f, acc1 = 0.f, acc2 = 0.f, acc3 = 0.f;
  for (int base = start; base < end; base += 16) {
    int ea = base + eoff, eb = base + 8 + eoff;
    int sa_ = 0, sb_ = 0;
    float wa = 0.f, wb = 0.f;
    if (ea < end) {
      sa_ = ssrc[ea];
      wa = __expf(lrelu(as1[(size_t)sa_ * 8 + hA] + ad_h));
    }
    if (eb < end) {
      sb_ = ssrc[eb];
      wb = __expf(lrelu(as1[(size_t)sb_ * 8 + hA] + ad_h));
    }
    s_loc += wa + wb;
    uint2 u[16];
    float w16[16];
#pragma unroll
    for (int j = 0; j < 8; ++j) {
      int se = __shfl(sa_, j * 8);
      w16[j] = __shfl(wa, j * 8 + hB);
      u[j] = *(const uint2*)(h1 + (size_t)se * 256 + hB * 32 + cB);
    }
#pragma unroll
    for (int j = 0; j < 8; ++j) {
      int se = __shfl(sb_, j * 8);
      w16[8 + j] = __shfl(wb, j * 8 + hB);
      u[8 + j] = *(const uint2*)(h1 + (size_t)se * 256 + hB * 32 + cB);
    }
#pragma unroll
    for (int j = 0; j < 16; ++j) {
      float w = w16[j];
      acc0 = fmaf(w, bf2f((unsigned short)(u[j].x & 0xffffu)), acc0);
      acc1 = fmaf(w, bf2f((unsigned short)(u[j].x >> 16)), acc1);
      acc2 = fmaf(w, bf2f((unsigned short)(u[j].y & 0xffffu)), acc2);
      acc3 = fmaf(w, bf2f((unsigned short)(u[j].y >> 16)), acc3);
    }
  }
  s_loc += __shfl_xor(s_loc, 8);
  s_loc += __shfl_xor(s_loc, 16);
  s_loc += __shfl_xor(s_loc, 32);
  const float inv_s = 1.f / (s_loc + 1e-16f);
  const float inv_sB = __shfl(inv_s, hB);  // lane hB holds s for head hB (its hA == hB)
  acc0 *= inv_sB; acc1 *= inv_sB; acc2 *= inv_sB; acc3 *= inv_sB;
  const int col = hB * 32 + cB;
  float av[4] = {acc0, acc1, acc2, acc3};
  float tp0 = 0.f, tp1 = 0.f;
  for (int j = 0; j < 4; ++j) {
    float v = av[j] + b1[col + j];
    v = v > 0.f ? v : (__expf(v) - 1.f);  // ELU
    tp0 = fmaf(v, W2[(col + j) * 2 + 0], tp0);
    tp1 = fmaf(v, W2[(col + j) * 2 + 1], tp1);
  }
  for (int off = 32; off >= 1; off >>= 1) {
    tp0 += __shfl_xor(tp0, off);
    tp1 += __shfl_xor(tp1, off);
  }
  if (lane == 0) {
    t_out[(size_t)dst * 2 + 0] = tp0;
    t_out[(size_t)dst * 2 + 1] = tp1;
    s2_out[dst] = tp0 * a2s[0] + tp1 * a2s[1];
    d2_out[dst] = tp0 * a2d[0] + tp1 * a2d[1];
  }
}

// ---------------- Layer-2 aggregation: single fused pass (thread per dst) ----------------
__global__ void k_agg2(const int* __restrict__ row_ptr, const int* __restrict__ ssrc,
                       const float* __restrict__ t_in, const float* __restrict__ s2,
                       const float* __restrict__ d2, const float* __restrict__ b2,
                       float* __restrict__ out) {
  int n = blockIdx.x * blockDim.x + threadIdx.x;
  if (n >= NN) return;
  int st = row_ptr[n], en = row_ptr[n + 1];
  float dv = d2[n];
  float ssum = 0.f, o0 = 0.f, o1 = 0.f;
#pragma unroll 4
  for (int e = st; e < en; ++e) {
    int s = ssrc[e];
    float w = __expf(lrelu(s2[s] + dv));
    float2 tv = *(const float2*)(t_in + (size_t)s * 2);
    ssum += w;
    o0 = fmaf(w, tv.x, o0);
    o1 = fmaf(w, tv.y, o1);
  }
  float inv = 1.f / (ssum + 1e-16f);
  out[(size_t)n * 2 + 0] = o0 * inv + b2[0];
  out[(size_t)n * 2 + 1] = o1 * inv + b2[1];
}

extern "C" void kernel_launch(void* const* d_in, const int* in_sizes, int n_in,
                              void* d_out, int out_size, void* d_ws, size_t ws_size,
                              hipStream_t stream) {
  const float* x = (const float*)d_in[0];
  const int* ei = (const int*)d_in[1];
  // d_in[2] = batch (unused)
  const float* W1 = (const float*)d_in[3];
  const float* a1s = (const float*)d_in[4];
  const float* a1d = (const float*)d_in[5];
  const float* b1 = (const float*)d_in[6];
  const float* W2 = (const float*)d_in[7];
  const float* a2s = (const float*)d_in[8];
  const float* a2d = (const float*)d_in[9];
  const float* b2 = (const float*)d_in[10];
  float* out = (float*)d_out;

  char* ws = (char*)d_ws;
  size_t off = 0;
  auto alloc = [&](size_t bytes) -> void* {
    void* p = ws + off;
    off += (bytes + 255) & ~(size_t)255;
    return p;
  };
  int* counts = (int*)alloc((size_t)NN * 4);
  int* row_ptr = (int*)alloc((size_t)(NN + 1) * 4);
  int* pre = (int*)alloc((size_t)NN * 4);
  int* bsum = (int*)alloc((size_t)SCAN_B * 4);
  int* rank = (int*)alloc((size_t)ET * 4);
  int* ssrc = (int*)alloc((size_t)ET * 4);
  unsigned short* xh = (unsigned short*)alloc((size_t)NP * 128 * 2);
  unsigned short* xl = (unsigned short*)alloc((size_t)NP * 128 * 2);
  unsigned short* wh = (unsigned short*)alloc((size_t)32768 * 2);
  unsigned short* wl = (unsigned short*)alloc((size_t)32768 * 2);
  unsigned short* h1 = (unsigned short*)alloc((size_t)NN * 256 * 2);
  float* as1 = (float*)alloc((size_t)NN * 8 * 4);
  float* ad1 = (float*)alloc((size_t)NN * 8 * 4);
  float* t = (float*)alloc((size_t)NN * 2 * 4);
  float* s2 = (float*)alloc((size_t)NN * 4);
  float* d2v = (float*)alloc((size_t)NN * 4);
  (void)ws_size; (void)in_sizes; (void)n_in; (void)out_size;

  hipMemsetAsync(counts, 0, (size_t)NN * 4, stream);
  k_conv_x<<<(NP * 32 + 255) / 256, 256, 0, stream>>>(x, xh, xl);
  k_conv_w<<<128, 256, 0, stream>>>(W1, wh, wl);
  k_rank<<<(ET + 255) / 256, 256, 0, stream>>>(ei, counts, rank);
  k_scan_a<<<SCAN_B, 256, 0, stream>>>(counts, pre, bsum);
  k_scan_b<<<1, 256, 0, stream>>>(bsum, row_ptr);
  k_scan_c<<<SCAN_B, 256, 0, stream>>>(pre, bsum, row_ptr);
  k_place<<<(ET + 255) / 256, 256, 0, stream>>>(ei, row_ptr, rank, ssrc);
  k_gemm1<<<NP / 64, 256, 0, stream>>>(xh, xl, wh, wl, a1s, a1d, h1, as1, ad1);
  k_agg1<<<(NN + 3) / 4, 256, 0, stream>>>(row_ptr, ssrc, h1, as1, ad1, b1, W2, a2s, a2d, t, s2, d2v);
  k_agg2<<<(NN + 255) / 256, 256, 0, stream>>>(row_ptr, ssrc, t, s2, d2v, b2, out);
}

// Round 11
// 272.754 us; speedup vs baseline: 4.1272x; 1.0314x over previous
//
#include <hip/hip_runtime.h>

#define NN 50000
#define NP 50048  // padded to multiple of 64
#define NE 800000
#define ET (NE + NN)
#define NT4 (NN * 4)                  // replicated counter array length: 200000
#define RANK_B ((ET + 255) / 256)     // 3321
#define CONVW_B 128
#define CONVX_B (NP * 32 / 256)       // 6256 (exact)
#define FRONT_B (RANK_B + CONVW_B + CONVX_B)
#define SCAN4_B ((NT4 + 255) / 256)   // 782

typedef __attribute__((ext_vector_type(8))) short short8;
typedef __attribute__((ext_vector_type(4))) float f32x4;

static __device__ __forceinline__ float bf2f(unsigned short u) {
  union { unsigned int i; float f; } v; v.i = ((unsigned int)u) << 16; return v.f;
}
static __device__ __forceinline__ unsigned short f2bf(float f) {
  union { unsigned int i; float f; } v; v.f = f;
  unsigned int r = v.i + 0x7fffu + ((v.i >> 16) & 1u);
  return (unsigned short)(r >> 16);
}
static __device__ __forceinline__ float lrelu(float z) { return z > 0.f ? z : 0.2f * z; }

// ---------------- fused front: rank (4-way replicated counters) | conv_w | conv_x ----------------
__global__ void k_front(const int* __restrict__ ei, int* __restrict__ counts4,
                        int* __restrict__ rank, const float* __restrict__ W1,
                        unsigned short* __restrict__ wh, unsigned short* __restrict__ wl,
                        const float* __restrict__ x, unsigned short* __restrict__ xh,
                        unsigned short* __restrict__ xl) {
  const int b = blockIdx.x;
  const int tid = threadIdx.x;
  if (b < RANK_B) {
    int e = b * 256 + tid;
    if (e < ET) {
      int dst = (e < NE) ? ei[NE + e] : (e - NE);
      rank[e] = atomicAdd(&counts4[(dst << 2) | (e & 3)], 1);
    }
  } else if (b < RANK_B + CONVW_B) {
    int i = (b - RANK_B) * 256 + tid;  // i < 32768
    int k = i >> 8, n = i & 255;
    float v = W1[i];
    unsigned short hi = f2bf(v);
    wh[n * 128 + k] = hi;
    wl[n * 128 + k] = f2bf(v - bf2f(hi));
  } else {
    int i4 = (b - RANK_B - CONVW_B) * 256 + tid;  // i4 < NP*32 exactly
    int i = i4 * 4;
    int row = i >> 7;
    float4 v = (row < NN) ? *(const float4*)(x + i) : (float4){0.f, 0.f, 0.f, 0.f};
    float vv[4] = {v.x, v.y, v.z, v.w};
    ushort4 h, l;
    unsigned short* hp = (unsigned short*)&h;
    unsigned short* lp = (unsigned short*)&l;
#pragma unroll
    for (int j = 0; j < 4; ++j) {
      unsigned short hi = f2bf(vv[j]);
      hp[j] = hi;
      lp[j] = f2bf(vv[j] - bf2f(hi));
    }
    *(ushort4*)(xh + i) = h;
    *(ushort4*)(xl + i) = l;
  }
}

// ---------------- scan over flat replicated counts (NT4 elements) ----------------
__global__ __launch_bounds__(256) void k_scan_a(const int* __restrict__ counts4,
                                                int* __restrict__ pre_loc, int* __restrict__ bsum) {
  __shared__ int sa[256];
  __shared__ int sb[256];
  const int t = threadIdx.x;
  const int i = blockIdx.x * 256 + t;
  sa[t] = (i < NT4) ? counts4[i] : 0;
  __syncthreads();
  int* src = sa;
  int* dst = sb;
  for (int off = 1; off < 256; off <<= 1) {
    int v = src[t];
    if (t >= off) v += src[t - off];
    dst[t] = v;
    int* tmp = src; src = dst; dst = tmp;
    __syncthreads();
  }
  int excl = (t == 0) ? 0 : src[t - 1];
  if (i < NT4) pre_loc[i] = excl;
  if (t == 255) bsum[blockIdx.x] = src[255];
}

__global__ __launch_bounds__(1024) void k_scan_b(int* __restrict__ bsum, int* __restrict__ pre4) {
  __shared__ int sa[1024];
  __shared__ int sb[1024];
  const int t = threadIdx.x;
  sa[t] = (t < SCAN4_B) ? bsum[t] : 0;
  __syncthreads();
  int* src = sa;
  int* dst = sb;
  for (int off = 1; off < 1024; off <<= 1) {
    int v = src[t];
    if (t >= off) v += src[t - off];
    dst[t] = v;
    int* tmp = src; src = dst; dst = tmp;
    __syncthreads();
  }
  int excl = (t == 0) ? 0 : src[t - 1];
  if (t < SCAN4_B) bsum[t] = excl;
  if (t == 1023) pre4[NT4] = src[1023];  // total
}

__global__ __launch_bounds__(256) void k_scan_c(const int* __restrict__ pre_loc,
                                                const int* __restrict__ bsum,
                                                int* __restrict__ pre4) {
  int i = blockIdx.x * 256 + threadIdx.x;
  if (i >= NT4) return;
  pre4[i] = bsum[blockIdx.x] + pre_loc[i];
}

__global__ void k_place(const int* __restrict__ ei, const int* __restrict__ pre4,
                        const int* __restrict__ rank, int* __restrict__ ssrc) {
  int e = blockIdx.x * blockDim.x + threadIdx.x;
  if (e >= ET) return;
  int src = (e < NE) ? ei[e] : (e - NE);
  int dst = (e < NE) ? ei[NE + e] : (e - NE);
  ssrc[pre4[(dst << 2) | (e & 3)] + rank[e]] = src;
}

// ---------------- Layer-1 GEMM via MFMA bf16x2 (3-pass split) ----------------
__global__ __launch_bounds__(256) void k_gemm1(
    const unsigned short* __restrict__ xh, const unsigned short* __restrict__ xl,
    const unsigned short* __restrict__ wh, const unsigned short* __restrict__ wl,
    const float* __restrict__ a1s, const float* __restrict__ a1d,
    unsigned short* __restrict__ h1, float* __restrict__ as1, float* __restrict__ ad1) {
  __shared__ unsigned short hst[64][264];
  const int tid = threadIdx.x;
  const int w = tid >> 6, lane = tid & 63;
  const int quad = lane >> 4, m16 = lane & 15;
  const int row0 = blockIdx.x * 64;
  const int koff = quad * 8;

  f32x4 acc[4][4];
  for (int mt = 0; mt < 4; ++mt)
    for (int nt = 0; nt < 4; ++nt) acc[mt][nt] = (f32x4){0.f, 0.f, 0.f, 0.f};

  for (int kt = 0; kt < 4; ++kt) {
    short8 ah[4], al[4], bh[4], bl[4];
    for (int mt = 0; mt < 4; ++mt) {
      size_t ra = (size_t)(row0 + mt * 16 + m16) * 128 + kt * 32 + koff;
      ah[mt] = *(const short8*)(xh + ra);
      al[mt] = *(const short8*)(xl + ra);
    }
    for (int nt = 0; nt < 4; ++nt) {
      size_t rb = (size_t)(w * 64 + nt * 16 + m16) * 128 + kt * 32 + koff;
      bh[nt] = *(const short8*)(wh + rb);
      bl[nt] = *(const short8*)(wl + rb);
    }
    for (int mt = 0; mt < 4; ++mt)
      for (int nt = 0; nt < 4; ++nt) {
        acc[mt][nt] = __builtin_amdgcn_mfma_f32_16x16x32_bf16(ah[mt], bh[nt], acc[mt][nt], 0, 0, 0);
        acc[mt][nt] = __builtin_amdgcn_mfma_f32_16x16x32_bf16(ah[mt], bl[nt], acc[mt][nt], 0, 0, 0);
        acc[mt][nt] = __builtin_amdgcn_mfma_f32_16x16x32_bf16(al[mt], bh[nt], acc[mt][nt], 0, 0, 0);
      }
  }
  for (int mt = 0; mt < 4; ++mt)
    for (int nt = 0; nt < 4; ++nt) {
      int c = w * 64 + nt * 16 + m16;
      int rb = mt * 16 + quad * 4;
      for (int r = 0; r < 4; ++r) hst[rb + r][c] = f2bf(acc[mt][nt][r]);
    }
  __syncthreads();
  for (int p = 0; p < 8; ++p) {
    int idx = p * 256 + tid;
    int row = idx >> 5, u4 = idx & 31;
    int grow = row0 + row;
    if (grow < NN) {
      uint4 v = *(const uint4*)&hst[row][u4 * 8];
      *(uint4*)(h1 + (size_t)grow * 256 + u4 * 8) = v;
    }
  }
  for (int p = 0; p < 2; ++p) {
    int id = p * 256 + tid;
    int row = id >> 3, head = id & 7;
    int grow = row0 + row;
    if (grow < NN) {
      float sa = 0.f, sd = 0.f;
      for (int c = 0; c < 32; ++c) {
        float hv = bf2f(hst[row][head * 32 + c]);
        sa = fmaf(hv, a1s[head * 32 + c], sa);
        sd = fmaf(hv, a1d[head * 32 + c], sd);
      }
      as1[(size_t)grow * 8 + head] = sa;
      ad1[(size_t)grow * 8 + head] = sd;
    }
  }
}

// ---------------- Layer-1 aggregation: single fused pass, 16-edge batches ----------------
__global__ __launch_bounds__(256) void k_agg1(
    const int* __restrict__ pre4, const int* __restrict__ ssrc,
    const unsigned short* __restrict__ h1, const float* __restrict__ as1,
    const float* __restrict__ ad1, const float* __restrict__ b1,
    const float* __restrict__ W2, const float* __restrict__ a2s,
    const float* __restrict__ a2d, float* __restrict__ t_out,
    float* __restrict__ s2_out, float* __restrict__ d2_out) {
  const int lane = threadIdx.x & 63;
  const int dst = (int)((blockIdx.x * blockDim.x + threadIdx.x) >> 6);
  if (dst >= NN) return;  // wave-uniform
  const int start = pre4[dst << 2], end = pre4[(dst + 1) << 2];
  const int hA = lane & 7;
  const int eoff = lane >> 3;
  const int hB = lane >> 3;
  const int cB = (lane & 7) * 4;
  const float ad_h = ad1[(size_t)dst * 8 + hA];
  float s_loc = 0.f;
  float acc0 = 0.f, acc1 = 0.f, acc2 = 0.f, acc3 = 0.f;
  for (int base = start; base < end; base += 16) {
    int ea = base + eoff, eb = base + 8 + eoff;
    int sa_ = 0, sb_ = 0;
    float wa = 0.f, wb = 0.f;
    if (ea < end) {
      sa_ = ssrc[ea];
      wa = __expf(lrelu(as1[(size_t)sa_ * 8 + hA] + ad_h));
    }
    if (eb < end) {
      sb_ = ssrc[eb];
      wb = __expf(lrelu(as1[(size_t)sb_ * 8 + hA] + ad_h));
    }
    s_loc += wa + wb;
    uint2 u[16];
    float w16[16];
#pragma unroll
    for (int j = 0; j < 8; ++j) {
      int se = __shfl(sa_, j * 8);
      w16[j] = __shfl(wa, j * 8 + hB);
      u[j] = *(const uint2*)(h1 + (size_t)se * 256 + hB * 32 + cB);
    }
#pragma unroll
    for (int j = 0; j < 8; ++j) {
      int se = __shfl(sb_, j * 8);
      w16[8 + j] = __shfl(wb, j * 8 + hB);
      u[8 + j] = *(const uint2*)(h1 + (size_t)se * 256 + hB * 32 + cB);
    }
#pragma unroll
    for (int j = 0; j < 16; ++j) {
      float w = w16[j];
      acc0 = fmaf(w, bf2f((unsigned short)(u[j].x & 0xffffu)), acc0);
      acc1 = fmaf(w, bf2f((unsigned short)(u[j].x >> 16)), acc1);
      acc2 = fmaf(w, bf2f((unsigned short)(u[j].y & 0xffffu)), acc2);
      acc3 = fmaf(w, bf2f((unsigned short)(u[j].y >> 16)), acc3);
    }
  }
  s_loc += __shfl_xor(s_loc, 8);
  s_loc += __shfl_xor(s_loc, 16);
  s_loc += __shfl_xor(s_loc, 32);
  const float inv_s = 1.f / (s_loc + 1e-16f);
  const float inv_sB = __shfl(inv_s, hB);  // lane hB holds s for head hB (its hA == hB)
  acc0 *= inv_sB; acc1 *= inv_sB; acc2 *= inv_sB; acc3 *= inv_sB;
  const int col = hB * 32 + cB;
  float av[4] = {acc0, acc1, acc2, acc3};
  float tp0 = 0.f, tp1 = 0.f;
  for (int j = 0; j < 4; ++j) {
    float v = av[j] + b1[col + j];
    v = v > 0.f ? v : (__expf(v) - 1.f);  // ELU
    tp0 = fmaf(v, W2[(col + j) * 2 + 0], tp0);
    tp1 = fmaf(v, W2[(col + j) * 2 + 1], tp1);
  }
  for (int off = 32; off >= 1; off >>= 1) {
    tp0 += __shfl_xor(tp0, off);
    tp1 += __shfl_xor(tp1, off);
  }
  if (lane == 0) {
    t_out[(size_t)dst * 2 + 0] = tp0;
    t_out[(size_t)dst * 2 + 1] = tp1;
    s2_out[dst] = tp0 * a2s[0] + tp1 * a2s[1];
    d2_out[dst] = tp0 * a2d[0] + tp1 * a2d[1];
  }
}

// ---------------- Layer-2 aggregation: 8 lanes per dst ----------------
__global__ __launch_bounds__(256) void k_agg2(
    const int* __restrict__ pre4, const int* __restrict__ ssrc,
    const float* __restrict__ t_in, const float* __restrict__ s2,
    const float* __restrict__ d2, const float* __restrict__ b2,
    float* __restrict__ out) {
  int gid = blockIdx.x * 256 + threadIdx.x;
  int n = gid >> 3;
  int l8 = threadIdx.x & 7;
  if (n >= NN) return;
  int st = pre4[n << 2], en = pre4[(n + 1) << 2];
  float dv = d2[n];
  float ssum = 0.f, o0 = 0.f, o1 = 0.f;
  for (int e = st + l8; e < en; e += 8) {
    int s = ssrc[e];
    float w = __expf(lrelu(s2[s] + dv));
    float2 tv = *(const float2*)(t_in + (size_t)s * 2);
    ssum += w;
    o0 = fmaf(w, tv.x, o0);
    o1 = fmaf(w, tv.y, o1);
  }
  ssum += __shfl_xor(ssum, 1); o0 += __shfl_xor(o0, 1); o1 += __shfl_xor(o1, 1);
  ssum += __shfl_xor(ssum, 2); o0 += __shfl_xor(o0, 2); o1 += __shfl_xor(o1, 2);
  ssum += __shfl_xor(ssum, 4); o0 += __shfl_xor(o0, 4); o1 += __shfl_xor(o1, 4);
  if (l8 == 0) {
    float inv = 1.f / (ssum + 1e-16f);
    out[(size_t)n * 2 + 0] = o0 * inv + b2[0];
    out[(size_t)n * 2 + 1] = o1 * inv + b2[1];
  }
}

extern "C" void kernel_launch(void* const* d_in, const int* in_sizes, int n_in,
                              void* d_out, int out_size, void* d_ws, size_t ws_size,
                              hipStream_t stream) {
  const float* x = (const float*)d_in[0];
  const int* ei = (const int*)d_in[1];
  // d_in[2] = batch (unused)
  const float* W1 = (const float*)d_in[3];
  const float* a1s = (const float*)d_in[4];
  const float* a1d = (const float*)d_in[5];
  const float* b1 = (const float*)d_in[6];
  const float* W2 = (const float*)d_in[7];
  const float* a2s = (const float*)d_in[8];
  const float* a2d = (const float*)d_in[9];
  const float* b2 = (const float*)d_in[10];
  float* out = (float*)d_out;

  char* ws = (char*)d_ws;
  size_t off = 0;
  auto alloc = [&](size_t bytes) -> void* {
    void* p = ws + off;
    off += (bytes + 255) & ~(size_t)255;
    return p;
  };
  int* counts4 = (int*)alloc((size_t)NT4 * 4);
  int* pre_loc = (int*)alloc((size_t)NT4 * 4);
  int* bsum = (int*)alloc((size_t)SCAN4_B * 4);
  int* pre4 = (int*)alloc((size_t)(NT4 + 1) * 4);
  int* rank = (int*)alloc((size_t)ET * 4);
  int* ssrc = (int*)alloc((size_t)ET * 4);
  unsigned short* xh = (unsigned short*)alloc((size_t)NP * 128 * 2);
  unsigned short* xl = (unsigned short*)alloc((size_t)NP * 128 * 2);
  unsigned short* wh = (unsigned short*)alloc((size_t)32768 * 2);
  unsigned short* wl = (unsigned short*)alloc((size_t)32768 * 2);
  unsigned short* h1 = (unsigned short*)alloc((size_t)NN * 256 * 2);
  float* as1 = (float*)alloc((size_t)NN * 8 * 4);
  float* ad1 = (float*)alloc((size_t)NN * 8 * 4);
  float* t = (float*)alloc((size_t)NN * 2 * 4);
  float* s2 = (float*)alloc((size_t)NN * 4);
  float* d2v = (float*)alloc((size_t)NN * 4);
  (void)ws_size; (void)in_sizes; (void)n_in; (void)out_size;

  hipMemsetAsync(counts4, 0, (size_t)NT4 * 4, stream);
  k_front<<<FRONT_B, 256, 0, stream>>>(ei, counts4, rank, W1, wh, wl, x, xh, xl);
  k_gemm1<<<NP / 64, 256, 0, stream>>>(xh, xl, wh, wl, a1s, a1d, h1, as1, ad1);
  k_scan_a<<<SCAN4_B, 256, 0, stream>>>(counts4, pre_loc, bsum);
  k_scan_b<<<1, 1024, 0, stream>>>(bsum, pre4);
  k_scan_c<<<SCAN4_B, 256, 0, stream>>>(pre_loc, bsum, pre4);
  k_place<<<(ET + 255) / 256, 256, 0, stream>>>(ei, pre4, rank, ssrc);
  k_agg1<<<(NN + 3) / 4, 256, 0, stream>>>(pre4, ssrc, h1, as1, ad1, b1, W2, a2s, a2d, t, s2, d2v);
  k_agg2<<<(NN * 8 + 255) / 256, 256, 0, stream>>>(pre4, ssrc, t, s2, d2v, b2, out);
}

// Round 12
// 268.708 us; speedup vs baseline: 4.1893x; 1.0151x over previous
//
#include <hip/hip_runtime.h>

#define NN 50000
#define NP 50048  // padded to multiple of 64
#define NE 800000
#define ET (NE + NN)
#define RANK_B ((ET + 255) / 256)     // 3321
#define CONVW_B 128
#define CONVX_B (NP * 32 / 256)       // 6256 (exact)
#define FRONT_B (RANK_B + CONVW_B + CONVX_B)
#define SCAN_B ((NN + 255) / 256)     // 196
#define PLACE_B ((ET + 255) / 256)    // 3321
#define GEMM_B (NP / 64)              // 782
#define MID_B (PLACE_B + GEMM_B)

typedef __attribute__((ext_vector_type(8))) short short8;
typedef __attribute__((ext_vector_type(4))) float f32x4;

static __device__ __forceinline__ float bf2f(unsigned short u) {
  union { unsigned int i; float f; } v; v.i = ((unsigned int)u) << 16; return v.f;
}
static __device__ __forceinline__ unsigned short f2bf(float f) {
  union { unsigned int i; float f; } v; v.f = f;
  unsigned int r = v.i + 0x7fffu + ((v.i >> 16) & 1u);
  return (unsigned short)(r >> 16);
}
static __device__ __forceinline__ float lrelu(float z) { return z > 0.f ? z : 0.2f * z; }

// ---------------- fused front: rank | conv_w | conv_x ----------------
__global__ void k_front(const int* __restrict__ ei, int* __restrict__ counts,
                        int* __restrict__ rank, const float* __restrict__ W1,
                        unsigned short* __restrict__ wh, unsigned short* __restrict__ wl,
                        const float* __restrict__ x, unsigned short* __restrict__ xh,
                        unsigned short* __restrict__ xl) {
  const int b = blockIdx.x;
  const int tid = threadIdx.x;
  if (b < RANK_B) {
    int e = b * 256 + tid;
    if (e < ET) {
      int dst = (e < NE) ? ei[NE + e] : (e - NE);
      rank[e] = atomicAdd(&counts[dst], 1);
    }
  } else if (b < RANK_B + CONVW_B) {
    int i = (b - RANK_B) * 256 + tid;  // i < 32768
    int k = i >> 8, n = i & 255;
    float v = W1[i];
    unsigned short hi = f2bf(v);
    wh[n * 128 + k] = hi;
    wl[n * 128 + k] = f2bf(v - bf2f(hi));
  } else {
    int i4 = (b - RANK_B - CONVW_B) * 256 + tid;  // i4 < NP*32 exactly
    int i = i4 * 4;
    int row = i >> 7;
    float4 v = (row < NN) ? *(const float4*)(x + i) : (float4){0.f, 0.f, 0.f, 0.f};
    float vv[4] = {v.x, v.y, v.z, v.w};
    ushort4 h, l;
    unsigned short* hp = (unsigned short*)&h;
    unsigned short* lp = (unsigned short*)&l;
#pragma unroll
    for (int j = 0; j < 4; ++j) {
      unsigned short hi = f2bf(vv[j]);
      hp[j] = hi;
      lp[j] = f2bf(vv[j] - bf2f(hi));
    }
    *(ushort4*)(xh + i) = h;
    *(ushort4*)(xl + i) = l;
  }
}

// ---------------- scan over counts (NN elements) ----------------
__global__ __launch_bounds__(256) void k_scan_a(const int* __restrict__ counts,
                                                int* __restrict__ pre_loc, int* __restrict__ bsum) {
  __shared__ int sa[256];
  __shared__ int sb[256];
  const int t = threadIdx.x;
  const int i = blockIdx.x * 256 + t;
  sa[t] = (i < NN) ? counts[i] : 0;
  __syncthreads();
  int* src = sa;
  int* dst = sb;
  for (int off = 1; off < 256; off <<= 1) {
    int v = src[t];
    if (t >= off) v += src[t - off];
    dst[t] = v;
    int* tmp = src; src = dst; dst = tmp;
    __syncthreads();
  }
  int excl = (t == 0) ? 0 : src[t - 1];
  if (i < NN) pre_loc[i] = excl;
  if (t == 255) bsum[blockIdx.x] = src[255];
}

__global__ __launch_bounds__(256) void k_scan_b(int* __restrict__ bsum, int* __restrict__ row_ptr) {
  __shared__ int sa[256];
  __shared__ int sb[256];
  const int t = threadIdx.x;
  sa[t] = (t < SCAN_B) ? bsum[t] : 0;
  __syncthreads();
  int* src = sa;
  int* dst = sb;
  for (int off = 1; off < 256; off <<= 1) {
    int v = src[t];
    if (t >= off) v += src[t - off];
    dst[t] = v;
    int* tmp = src; src = dst; dst = tmp;
    __syncthreads();
  }
  int excl = (t == 0) ? 0 : src[t - 1];
  if (t < SCAN_B) bsum[t] = excl;
  if (t == 255) row_ptr[NN] = src[255];
}

__global__ __launch_bounds__(256) void k_scan_c(const int* __restrict__ pre_loc,
                                                const int* __restrict__ bsum,
                                                int* __restrict__ row_ptr) {
  int i = blockIdx.x * 256 + threadIdx.x;
  if (i >= NN) return;
  row_ptr[i] = bsum[blockIdx.x] + pre_loc[i];
}

// ---------------- fused mid: place | gemm1 (bf16x2 MFMA) ----------------
__global__ __launch_bounds__(256) void k_mid(
    const int* __restrict__ ei, const int* __restrict__ row_ptr,
    const int* __restrict__ rank, int* __restrict__ ssrc,
    const unsigned short* __restrict__ xh, const unsigned short* __restrict__ xl,
    const unsigned short* __restrict__ wh, const unsigned short* __restrict__ wl,
    const float* __restrict__ a1s, const float* __restrict__ a1d,
    unsigned short* __restrict__ h1, float* __restrict__ as1, float* __restrict__ ad1) {
  __shared__ unsigned short hst[64][264];
  const int tid = threadIdx.x;
  if (blockIdx.x < PLACE_B) {
    int e = blockIdx.x * 256 + tid;
    if (e < ET) {
      int src = (e < NE) ? ei[e] : (e - NE);
      int dst = (e < NE) ? ei[NE + e] : (e - NE);
      ssrc[row_ptr[dst] + rank[e]] = src;
    }
    return;
  }
  const int gb = blockIdx.x - PLACE_B;
  const int w = tid >> 6, lane = tid & 63;
  const int quad = lane >> 4, m16 = lane & 15;
  const int row0 = gb * 64;
  const int koff = quad * 8;

  f32x4 acc[4][4];
  for (int mt = 0; mt < 4; ++mt)
    for (int nt = 0; nt < 4; ++nt) acc[mt][nt] = (f32x4){0.f, 0.f, 0.f, 0.f};

  for (int kt = 0; kt < 4; ++kt) {
    short8 ah[4], al[4], bh[4], bl[4];
    for (int mt = 0; mt < 4; ++mt) {
      size_t ra = (size_t)(row0 + mt * 16 + m16) * 128 + kt * 32 + koff;
      ah[mt] = *(const short8*)(xh + ra);
      al[mt] = *(const short8*)(xl + ra);
    }
    for (int nt = 0; nt < 4; ++nt) {
      size_t rb = (size_t)(w * 64 + nt * 16 + m16) * 128 + kt * 32 + koff;
      bh[nt] = *(const short8*)(wh + rb);
      bl[nt] = *(const short8*)(wl + rb);
    }
    for (int mt = 0; mt < 4; ++mt)
      for (int nt = 0; nt < 4; ++nt) {
        acc[mt][nt] = __builtin_amdgcn_mfma_f32_16x16x32_bf16(ah[mt], bh[nt], acc[mt][nt], 0, 0, 0);
        acc[mt][nt] = __builtin_amdgcn_mfma_f32_16x16x32_bf16(ah[mt], bl[nt], acc[mt][nt], 0, 0, 0);
        acc[mt][nt] = __builtin_amdgcn_mfma_f32_16x16x32_bf16(al[mt], bh[nt], acc[mt][nt], 0, 0, 0);
      }
  }
  for (int mt = 0; mt < 4; ++mt)
    for (int nt = 0; nt < 4; ++nt) {
      int c = w * 64 + nt * 16 + m16;
      int rb = mt * 16 + quad * 4;
      for (int r = 0; r < 4; ++r) hst[rb + r][c] = f2bf(acc[mt][nt][r]);
    }
  __syncthreads();
  for (int p = 0; p < 8; ++p) {
    int idx = p * 256 + tid;
    int row = idx >> 5, u4 = idx & 31;
    int grow = row0 + row;
    if (grow < NN) {
      uint4 v = *(const uint4*)&hst[row][u4 * 8];
      *(uint4*)(h1 + (size_t)grow * 256 + u4 * 8) = v;
    }
  }
  for (int p = 0; p < 2; ++p) {
    int id = p * 256 + tid;
    int row = id >> 3, head = id & 7;
    int grow = row0 + row;
    if (grow < NN) {
      float sa = 0.f, sd = 0.f;
      for (int c = 0; c < 32; ++c) {
        float hv = bf2f(hst[row][head * 32 + c]);
        sa = fmaf(hv, a1s[head * 32 + c], sa);
        sd = fmaf(hv, a1d[head * 32 + c], sd);
      }
      as1[(size_t)grow * 8 + head] = sa;
      ad1[(size_t)grow * 8 + head] = sd;
    }
  }
}

// ---------------- Layer-1 aggregation: single fused pass, 16-edge batches ----------------
__global__ __launch_bounds__(256) void k_agg1(
    const int* __restrict__ row_ptr, const int* __restrict__ ssrc,
    const unsigned short* __restrict__ h1, const float* __restrict__ as1,
    const float* __restrict__ ad1, const float* __restrict__ b1,
    const float* __restrict__ W2, const float* __restrict__ a2s,
    const float* __restrict__ a2d, float* __restrict__ t_out,
    float* __restrict__ s2_out, float* __restrict__ d2_out) {
  const int lane = threadIdx.x & 63;
  const int dst = (int)((blockIdx.x * blockDim.x + threadIdx.x) >> 6);
  if (dst >= NN) return;  // wave-uniform
  const int start = row_ptr[dst], end = row_ptr[dst + 1];
  const int hA = lane & 7;
  const int eoff = lane >> 3;
  const int hB = lane >> 3;
  const int cB = (lane & 7) * 4;
  const float ad_h = ad1[(size_t)dst * 8 + hA];
  float s_loc = 0.f;
  float acc0 = 0.f, acc1 = 0.f, acc2 = 0.f, acc3 = 0.f;
  for (int base = start; base < end; base += 16) {
    int ea = base + eoff, eb = base + 8 + eoff;
    int sa_ = 0, sb_ = 0;
    float wa = 0.f, wb = 0.f;
    if (ea < end) {
      sa_ = ssrc[ea];
      wa = __expf(lrelu(as1[(size_t)sa_ * 8 + hA] + ad_h));
    }
    if (eb < end) {
      sb_ = ssrc[eb];
      wb = __expf(lrelu(as1[(size_t)sb_ * 8 + hA] + ad_h));
    }
    s_loc += wa + wb;
    uint2 u[16];
    float w16[16];
#pragma unroll
    for (int j = 0; j < 8; ++j) {
      int se = __shfl(sa_, j * 8);
      w16[j] = __shfl(wa, j * 8 + hB);
      u[j] = *(const uint2*)(h1 + (size_t)se * 256 + hB * 32 + cB);
    }
#pragma unroll
    for (int j = 0; j < 8; ++j) {
      int se = __shfl(sb_, j * 8);
      w16[8 + j] = __shfl(wb, j * 8 + hB);
      u[8 + j] = *(const uint2*)(h1 + (size_t)se * 256 + hB * 32 + cB);
    }
#pragma unroll
    for (int j = 0; j < 16; ++j) {
      float w = w16[j];
      acc0 = fmaf(w, bf2f((unsigned short)(u[j].x & 0xffffu)), acc0);
      acc1 = fmaf(w, bf2f((unsigned short)(u[j].x >> 16)), acc1);
      acc2 = fmaf(w, bf2f((unsigned short)(u[j].y & 0xffffu)), acc2);
      acc3 = fmaf(w, bf2f((unsigned short)(u[j].y >> 16)), acc3);
    }
  }
  s_loc += __shfl_xor(s_loc, 8);
  s_loc += __shfl_xor(s_loc, 16);
  s_loc += __shfl_xor(s_loc, 32);
  const float inv_s = 1.f / (s_loc + 1e-16f);
  const float inv_sB = __shfl(inv_s, hB);  // lane hB holds s for head hB (its hA == hB)
  acc0 *= inv_sB; acc1 *= inv_sB; acc2 *= inv_sB; acc3 *= inv_sB;
  const int col = hB * 32 + cB;
  float av[4] = {acc0, acc1, acc2, acc3};
  float tp0 = 0.f, tp1 = 0.f;
  for (int j = 0; j < 4; ++j) {
    float v = av[j] + b1[col + j];
    v = v > 0.f ? v : (__expf(v) - 1.f);  // ELU
    tp0 = fmaf(v, W2[(col + j) * 2 + 0], tp0);
    tp1 = fmaf(v, W2[(col + j) * 2 + 1], tp1);
  }
  for (int off = 32; off >= 1; off >>= 1) {
    tp0 += __shfl_xor(tp0, off);
    tp1 += __shfl_xor(tp1, off);
  }
  if (lane == 0) {
    t_out[(size_t)dst * 2 + 0] = tp0;
    t_out[(size_t)dst * 2 + 1] = tp1;
    s2_out[dst] = tp0 * a2s[0] + tp1 * a2s[1];
    d2_out[dst] = tp0 * a2d[0] + tp1 * a2d[1];
  }
}

// ---------------- Layer-2 aggregation: 8 lanes per dst ----------------
__global__ __launch_bounds__(256) void k_agg2(
    const int* __restrict__ row_ptr, const int* __restrict__ ssrc,
    const float* __restrict__ t_in, const float* __restrict__ s2,
    const float* __restrict__ d2, const float* __restrict__ b2,
    float* __restrict__ out) {
  int gid = blockIdx.x * 256 + threadIdx.x;
  int n = gid >> 3;
  int l8 = threadIdx.x & 7;
  if (n >= NN) return;
  int st = row_ptr[n], en = row_ptr[n + 1];
  float dv = d2[n];
  float ssum = 0.f, o0 = 0.f, o1 = 0.f;
  for (int e = st + l8; e < en; e += 8) {
    int s = ssrc[e];
    float w = __expf(lrelu(s2[s] + dv));
    float2 tv = *(const float2*)(t_in + (size_t)s * 2);
    ssum += w;
    o0 = fmaf(w, tv.x, o0);
    o1 = fmaf(w, tv.y, o1);
  }
  ssum += __shfl_xor(ssum, 1); o0 += __shfl_xor(o0, 1); o1 += __shfl_xor(o1, 1);
  ssum += __shfl_xor(ssum, 2); o0 += __shfl_xor(o0, 2); o1 += __shfl_xor(o1, 2);
  ssum += __shfl_xor(ssum, 4); o0 += __shfl_xor(o0, 4); o1 += __shfl_xor(o1, 4);
  if (l8 == 0) {
    float inv = 1.f / (ssum + 1e-16f);
    out[(size_t)n * 2 + 0] = o0 * inv + b2[0];
    out[(size_t)n * 2 + 1] = o1 * inv + b2[1];
  }
}

extern "C" void kernel_launch(void* const* d_in, const int* in_sizes, int n_in,
                              void* d_out, int out_size, void* d_ws, size_t ws_size,
                              hipStream_t stream) {
  const float* x = (const float*)d_in[0];
  const int* ei = (const int*)d_in[1];
  // d_in[2] = batch (unused)
  const float* W1 = (const float*)d_in[3];
  const float* a1s = (const float*)d_in[4];
  const float* a1d = (const float*)d_in[5];
  const float* b1 = (const float*)d_in[6];
  const float* W2 = (const float*)d_in[7];
  const float* a2s = (const float*)d_in[8];
  const float* a2d = (const float*)d_in[9];
  const float* b2 = (const float*)d_in[10];
  float* out = (float*)d_out;

  char* ws = (char*)d_ws;
  size_t off = 0;
  auto alloc = [&](size_t bytes) -> void* {
    void* p = ws + off;
    off += (bytes + 255) & ~(size_t)255;
    return p;
  };
  int* counts = (int*)alloc((size_t)NN * 4);
  int* pre_loc = (int*)alloc((size_t)NN * 4);
  int* bsum = (int*)alloc((size_t)SCAN_B * 4);
  int* row_ptr = (int*)alloc((size_t)(NN + 1) * 4);
  int* rank = (int*)alloc((size_t)ET * 4);
  int* ssrc = (int*)alloc((size_t)ET * 4);
  unsigned short* xh = (unsigned short*)alloc((size_t)NP * 128 * 2);
  unsigned short* xl = (unsigned short*)alloc((size_t)NP * 128 * 2);
  unsigned short* wh = (unsigned short*)alloc((size_t)32768 * 2);
  unsigned short* wl = (unsigned short*)alloc((size_t)32768 * 2);
  unsigned short* h1 = (unsigned short*)alloc((size_t)NN * 256 * 2);
  float* as1 = (float*)alloc((size_t)NN * 8 * 4);
  float* ad1 = (float*)alloc((size_t)NN * 8 * 4);
  float* t = (float*)alloc((size_t)NN * 2 * 4);
  float* s2 = (float*)alloc((size_t)NN * 4);
  float* d2v = (float*)alloc((size_t)NN * 4);
  (void)ws_size; (void)in_sizes; (void)n_in; (void)out_size;

  hipMemsetAsync(counts, 0, (size_t)NN * 4, stream);
  k_front<<<FRONT_B, 256, 0, stream>>>(ei, counts, rank, W1, wh, wl, x, xh, xl);
  k_scan_a<<<SCAN_B, 256, 0, stream>>>(counts, pre_loc, bsum);
  k_scan_b<<<1, 256, 0, stream>>>(bsum, row_ptr);
  k_scan_c<<<SCAN_B, 256, 0, stream>>>(pre_loc, bsum, row_ptr);
  k_mid<<<MID_B, 256, 0, stream>>>(ei, row_ptr, rank, ssrc, xh, xl, wh, wl, a1s, a1d, h1, as1, ad1);
  k_agg1<<<(NN + 3) / 4, 256, 0, stream>>>(row_ptr, ssrc, h1, as1, ad1, b1, W2, a2s, a2d, t, s2, d2v);
  k_agg2<<<(NN * 8 + 255) / 256, 256, 0, stream>>>(row_ptr, ssrc, t, s2, d2v, b2, out);
}